// Round 3
// baseline (663.221 us; speedup 1.0000x reference)
//
#include <hip/hip_runtime.h>
#include <hip/hip_bf16.h>
#include <math.h>

#define Tn 100
#define Bn 2048

__device__ __forceinline__ float sp_f(float x) {
    // jax.nn.softplus(x) = max(x,0) + log1p(exp(-|x|))
    float e = __expf(-fabsf(x));
    return fmaxf(x, 0.f) + __logf(1.f + e);
}
__device__ __forceinline__ float clamp6(float x) {
    return fminf(fmaxf(x, -6.f), 6.f);
}
// DPP cross-lane (pure VALU). After xor1+xor2 every quad is uniform, so the
// xor4 stage may be ANY cross-quad-within-8 permutation (row_half_mirror) and
// xor8 within a 16-row is row_ror:8 (i -> i^8 exactly).
__device__ __forceinline__ float dpp_xor1(float x) {
    return __int_as_float(__builtin_amdgcn_mov_dpp(__float_as_int(x), 0xB1, 0xF, 0xF, 1));
}
__device__ __forceinline__ float dpp_xor2(float x) {
    return __int_as_float(__builtin_amdgcn_mov_dpp(__float_as_int(x), 0x4E, 0xF, 0xF, 1));
}
__device__ __forceinline__ float dpp_hmirror(float x) {
    return __int_as_float(__builtin_amdgcn_mov_dpp(__float_as_int(x), 0x141, 0xF, 0xF, 1));
}
__device__ __forceinline__ float dpp_ror8(float x) {
    return __int_as_float(__builtin_amdgcn_mov_dpp(__float_as_int(x), 0x128, 0xF, 0xF, 1));
}
template <int OFF>
__device__ __forceinline__ float swz(float x) {
    return __int_as_float(__builtin_amdgcn_ds_swizzle(__float_as_int(x), OFF));
}

// ---------------------------------------------------------------- encoder
__global__ __launch_bounds__(256) void enc_kernel(
    const float* __restrict__ xs,
    const float* __restrict__ eW1, const float* __restrict__ eb1,
    const float* __restrict__ eW2, const float* __restrict__ eb2,
    const float* __restrict__ eW3, const float* __restrict__ eb3,
    float* __restrict__ ctx, float* __restrict__ qm, float* __restrict__ qs)
{
    __shared__ float w[5925];
    for (int i = threadIdx.x; i < 4500; i += 256) w[i] = eW1[i];
    if (threadIdx.x < 30) w[4500 + threadIdx.x] = eb1[threadIdx.x];
    for (int i = threadIdx.x; i < 900; i += 256) w[4530 + i] = eW2[i];
    if (threadIdx.x < 30) w[5430 + threadIdx.x] = eb2[threadIdx.x];
    for (int i = threadIdx.x; i < 450; i += 256) w[5460 + i] = eW3[i];
    if (threadIdx.x < 15) w[5910 + threadIdx.x] = eb3[threadIdx.x];
    __syncthreads();

    int gid = blockIdx.x * 256 + threadIdx.x;          // = tt*Bn + b
    const float* x = xs + (size_t)gid * 150;

    float h1[30];
#pragma unroll
    for (int j = 0; j < 30; ++j) h1[j] = w[4500 + j];
    for (int i = 0; i < 150; i += 2) {
        float2 xv = *reinterpret_cast<const float2*>(x + i);
#pragma unroll
        for (int j = 0; j < 30; ++j) h1[j] = fmaf(xv.x, w[i * 30 + j], h1[j]);
#pragma unroll
        for (int j = 0; j < 30; ++j) h1[j] = fmaf(xv.y, w[(i + 1) * 30 + j], h1[j]);
    }
#pragma unroll
    for (int j = 0; j < 30; ++j) h1[j] = sp_f(h1[j]);

    float h2[30];
#pragma unroll
    for (int j = 0; j < 30; ++j) h2[j] = w[5430 + j];
    for (int j1 = 0; j1 < 30; ++j1) {
        float hv = h1[j1];
#pragma unroll
        for (int j = 0; j < 30; ++j) h2[j] = fmaf(hv, w[4530 + j1 * 30 + j], h2[j]);
    }
#pragma unroll
    for (int j = 0; j < 30; ++j) h2[j] = sp_f(h2[j]);

    float o12 = w[5910 + 12], o13 = w[5910 + 13], o14 = w[5910 + 14];
#pragma unroll
    for (int j2 = 0; j2 < 30; ++j2) {
        o12 = fmaf(h2[j2], w[5460 + j2 * 15 + 12], o12);
        o13 = fmaf(h2[j2], w[5460 + j2 * 15 + 13], o13);
        o14 = fmaf(h2[j2], w[5460 + j2 * 15 + 14], o14);
    }
    float* cp = ctx + (size_t)gid * 3;
    cp[0] = o12; cp[1] = o13; cp[2] = o14;

    if (blockIdx.x < 8) {   // tt == 0
        int b = gid;
        float o[12];
#pragma unroll
        for (int j3 = 0; j3 < 12; ++j3) o[j3] = w[5910 + j3];
#pragma unroll
        for (int j2 = 0; j2 < 30; ++j2) {
            float hv = h2[j2];
#pragma unroll
            for (int j3 = 0; j3 < 12; ++j3) o[j3] = fmaf(hv, w[5460 + j2 * 15 + j3], o[j3]);
        }
#pragma unroll
        for (int d = 0; d < 6; ++d) { qm[b * 6 + d] = o[d]; qs[b * 6 + d] = o[6 + d]; }
    }
}

// ---------------------------------------------------------- z0 + KL reduction
__global__ __launch_bounds__(256) void z0kl_kernel(
    const float* __restrict__ qm, const float* __restrict__ qs,
    const float* __restrict__ eps0, const float* __restrict__ pm,
    const float* __restrict__ ps, float* __restrict__ zsb, float* __restrict__ acc)
{
    int idx = blockIdx.x * 256 + threadIdx.x;   // < Bn*6
    int d = idx % 6;
    float m = qm[idx], lsq = qs[idx];
    float sq = __expf(clamp6(lsq));
    zsb[idx] = fmaf(sq, eps0[idx], m);          // zs[0][b][d]
    float spz = __expf(clamp6(ps[d]));
    float dm = m - pm[d];
    float kl = __logf(spz / sq) + (sq * sq + dm * dm) / (2.f * spz * spz) - 0.5f;
#pragma unroll
    for (int mm = 1; mm <= 32; mm <<= 1) kl += __shfl_xor(kl, mm);
    __shared__ float red[4];
    if ((threadIdx.x & 63) == 0) red[threadIdx.x >> 6] = kl;
    __syncthreads();
    if (threadIdx.x == 0) atomicAdd(&acc[1], red[0] + red[1] + red[2] + red[3]);
}

// ------------------------------------------------------------------- SDE scan
// 16 lanes per chain, 4 chains per 64-thread block, grid=512 (2 waves/CU).
// All per-step data staged in LDS; all weights in registers (fits: no remat).
__global__ __launch_bounds__(64, 2) void scan_kernel(
    const float* __restrict__ ts, const float* __restrict__ dWall,
    const float* __restrict__ fW1, const float* __restrict__ fb1,
    const float* __restrict__ fW2, const float* __restrict__ fb2,
    const float* __restrict__ hW1, const float* __restrict__ hb1,
    const float* __restrict__ hW2, const float* __restrict__ hb2,
    const float* __restrict__ gW1, const float* __restrict__ gb1,
    const float* __restrict__ gW2, const float* __restrict__ gb2,
    const float* __restrict__ ctx, float* __restrict__ zsb, float* __restrict__ acc)
{
    int tid = threadIdx.x;
    int L = tid & 15;            // lane within chain group
    int g = tid >> 4;            // chain within block (0..3)
    int b0 = blockIdx.x * 4;
    int b = b0 + g;

    __shared__ float sm[3168 + 1584 + 104];
    float* sdW  = sm;            // [99][4][8]  (pad to 8 for b128 alignment)
    float* sctx = sm + 3168;     // [99][4][4]
    float* sts  = sm + 4752;     // [100]

    // ---- bulk staging (coalesced) -------------------------------------
    for (int idx = tid; idx < 99 * 12; idx += 64) {        // dW: 99*4c*3 float2
        int k = idx / 12, r = idx % 12, c = r / 3, e = r % 3;
        float2 v = *(const float2*)(dWall + ((size_t)k * Bn + b0 + c) * 6 + e * 2);
        *(float2*)&sdW[k * 32 + c * 8 + e * 2] = v;
    }
    for (int idx = tid; idx < 99 * 12; idx += 64) {        // ctx rows k+1
        int k = idx / 12, j = idx % 12, c = j / 3, e = j % 3;
        sctx[k * 16 + c * 4 + e] = ctx[((size_t)(k + 1) * Bn + b0) * 3 + j];
    }
    for (int idx = tid; idx < 99 * 4; idx += 64) {         // zero the pad
        int k = idx >> 2, c = idx & 3;
        sctx[k * 16 + c * 4 + 3] = 0.f;
    }
    for (int idx = tid; idx < Tn; idx += 64) sts[idx] = ts[idx];

    // ---- per-lane weight registers ------------------------------------
    int j0 = L, j1 = L + 16;
    bool v1 = (j1 < 30);
    float wfc[10][2], fb1c[2], whc[7][2], hb1c[2], wf2c[2][6], wh2c[2][6];
#pragma unroll
    for (int i = 0; i < 10; ++i) {
        wfc[i][0] = fW1[i * 30 + j0];
        wfc[i][1] = v1 ? fW1[i * 30 + j1] : 0.f;
    }
    fb1c[0] = fb1[j0]; fb1c[1] = v1 ? fb1[j1] : 0.f;
#pragma unroll
    for (int i = 0; i < 7; ++i) {
        whc[i][0] = hW1[i * 30 + j0];
        whc[i][1] = v1 ? hW1[i * 30 + j1] : 0.f;
    }
    hb1c[0] = hb1[j0]; hb1c[1] = v1 ? hb1[j1] : 0.f;
#pragma unroll
    for (int d = 0; d < 6; ++d) {
        wf2c[0][d] = fW2[j0 * 6 + d];
        wf2c[1][d] = v1 ? fW2[j1 * 6 + d] : 0.f;
        wh2c[0][d] = hW2[j0 * 6 + d];
        wh2c[1][d] = v1 ? hW2[j1 * 6 + d] : 0.f;
    }
    float fb2v[6];
#pragma unroll
    for (int d = 0; d < 6; ++d) fb2v[d] = fb2[d];

    // g-network: lanes 0..11 cover dim dL = L>>1, jj = (L&1) + 2u, u=0..14
    int dL = (L < 12) ? (L >> 1) : 0;
    bool gvalid = (L < 12);
    int jpar = L & 1;
    float w1a[15], w1b[15], wg2v[15], gb1v[15];
#pragma unroll
    for (int u = 0; u < 15; ++u) {
        int jj = jpar + 2 * u;
        w1a[u]  = gvalid ? gW1[dL * 60 + jj] : 0.f;        // gW1[d][0][jj]
        w1b[u]  = gvalid ? gW1[dL * 60 + 30 + jj] : 0.f;   // gW1[d][1][jj]
        wg2v[u] = gvalid ? gW2[dL * 30 + jj] : 0.f;
        gb1v[u] = gvalid ? gb1[dL * 30 + jj] : 0.f;
    }
    float gb2v = gb2[dL];
    float hb2q = hb2[dL];
    float wsel = gvalid ? 0.25f : 0.f;   // each dim appears on 2 lanes -> 2*0.25=0.5

    __syncthreads();

    float z[6];
#pragma unroll
    for (int d = 0; d < 6; ++d) z[d] = zsb[(size_t)b * 6 + d];
    float pacc = 0.f;

#pragma unroll 2
    for (int k = 0; k < Tn - 1; ++k) {
        float4 dw0 = *(float4*)&sdW[k * 32 + g * 8];
        float2 dw1 = *(float2*)&sdW[k * 32 + g * 8 + 4];
        float4 cv  = *(float4*)&sctx[k * 16 + g * 4];
        float t  = sts[k];
        float dt = sts[k + 1] - t;

        // own-dim z for g input
        float zq = z[0];
        zq = (dL == 1) ? z[1] : zq;
        zq = (dL == 2) ? z[2] : zq;
        zq = (dL == 3) ? z[3] : zq;
        zq = (dL == 4) ? z[4] : zq;
        zq = (dL == 5) ? z[5] : zq;

        // ---- g hidden (15 units/lane), 3-way accumulator split --------
        float ga0 = 0.f, ga1 = 0.f, ga2 = 0.f;
#pragma unroll
        for (int u = 0; u < 15; u += 3) {
            float A0 = fmaf(t, w1a[u], gb1v[u]);
            float A1 = fmaf(t, w1a[u + 1], gb1v[u + 1]);
            float A2 = fmaf(t, w1a[u + 2], gb1v[u + 2]);
            ga0 = fmaf(sp_f(fmaf(zq, w1b[u], A0)), wg2v[u], ga0);
            ga1 = fmaf(sp_f(fmaf(zq, w1b[u + 1], A1)), wg2v[u + 1], ga1);
            ga2 = fmaf(sp_f(fmaf(zq, w1b[u + 2], A2)), wg2v[u + 2], ga2);
        }
        float gpart = ga0 + ga1 + ga2;
        gpart += dpp_xor1(gpart);            // pair (2d,2d+1) -> full 30-sum
        float gacc = gpart + gb2v;
        float eg = __expf(-fabsf(gacc));
        float rden = __builtin_amdgcn_rcpf(1.f + eg);
        float gval = (gacc >= 0.f) ? rden : eg * rden;

        // ---- f / h hidden (2 cols/lane) -------------------------------
        float fh[2], hh[2];
#pragma unroll
        for (int r = 0; r < 2; ++r) {
            float a = fmaf(t, wfc[0][r], fb1c[r]);
#pragma unroll
            for (int i = 0; i < 6; ++i) a = fmaf(z[i], wfc[1 + i][r], a);
            a = fmaf(cv.x, wfc[7][r], a);
            a = fmaf(cv.y, wfc[8][r], a);
            a = fmaf(cv.z, wfc[9][r], a);
            fh[r] = sp_f(a);
            float ah = fmaf(t, whc[0][r], hb1c[r]);
#pragma unroll
            for (int i = 0; i < 6; ++i) ah = fmaf(z[i], whc[1 + i][r], ah);
            hh[r] = sp_f(ah);
        }
        // ---- layer-2 partials + 16-lane DPP butterfly -----------------
        float pf[6], ph[6];
#pragma unroll
        for (int d = 0; d < 6; ++d) {
            pf[d] = fmaf(fh[1], wf2c[1][d], fh[0] * wf2c[0][d]);
            ph[d] = fmaf(hh[1], wh2c[1][d], hh[0] * wh2c[0][d]);
        }
#pragma unroll
        for (int d = 0; d < 6; ++d) { pf[d] += dpp_xor1(pf[d]);    ph[d] += dpp_xor1(ph[d]); }
#pragma unroll
        for (int d = 0; d < 6; ++d) { pf[d] += dpp_xor2(pf[d]);    ph[d] += dpp_xor2(ph[d]); }
#pragma unroll
        for (int d = 0; d < 6; ++d) { pf[d] += dpp_hmirror(pf[d]); ph[d] += dpp_hmirror(ph[d]); }
#pragma unroll
        for (int d = 0; d < 6; ++d) { pf[d] += dpp_ror8(pf[d]);    ph[d] += dpp_ror8(ph[d]); }

        float fv[6];
#pragma unroll
        for (int d = 0; d < 6; ++d) fv[d] = pf[d] + fb2v[d];

        // ---- broadcast g_d (at lane 2d of each 16-group) --------------
        // BitMode: src = (i & 0x10) | 2d  -> offset = (2d<<5) | 0x10
        float gl[6];
        gl[0] = swz<0x010>(gval); gl[1] = swz<0x050>(gval); gl[2] = swz<0x090>(gval);
        gl[3] = swz<0x0D0>(gval); gl[4] = swz<0x110>(gval); gl[5] = swz<0x150>(gval);

        // ---- own-dim u, private pacc ----------------------------------
        float fvq = fv[0], phq = ph[0], glq = gl[0];
        fvq = (dL == 1) ? fv[1] : fvq; phq = (dL == 1) ? ph[1] : phq; glq = (dL == 1) ? gl[1] : glq;
        fvq = (dL == 2) ? fv[2] : fvq; phq = (dL == 2) ? ph[2] : phq; glq = (dL == 2) ? gl[2] : glq;
        fvq = (dL == 3) ? fv[3] : fvq; phq = (dL == 3) ? ph[3] : phq; glq = (dL == 3) ? gl[3] : glq;
        fvq = (dL == 4) ? fv[4] : fvq; phq = (dL == 4) ? ph[4] : phq; glq = (dL == 4) ? gl[4] : glq;
        fvq = (dL == 5) ? fv[5] : fvq; phq = (dL == 5) ? ph[5] : phq; glq = (dL == 5) ? gl[5] : glq;
        float uq = (fvq - (phq + hb2q)) * __builtin_amdgcn_rcpf(glq);
        pacc = fmaf(wsel * dt, uq * uq, pacc);

        // ---- z update -------------------------------------------------
        float dwv[6] = { dw0.x, dw0.y, dw0.z, dw0.w, dw1.x, dw1.y };
#pragma unroll
        for (int d = 0; d < 6; ++d)
            z[d] = fmaf(gl[d], dwv[d], fmaf(fv[d], dt, z[d]));

        if (L == 0) {
            float* zp = zsb + ((size_t)(k + 1) * Bn + b) * 6;
            *(float2*)(zp)     = make_float2(z[0], z[1]);
            *(float2*)(zp + 2) = make_float2(z[2], z[3]);
            *(float2*)(zp + 4) = make_float2(z[4], z[5]);
        }
    }
    // wave-wide sum of private pacc (covers all 4 chains of this block)
#pragma unroll
    for (int mm = 1; mm <= 32; mm <<= 1) pacc += __shfl_xor(pacc, mm);
    if (tid == 0) atomicAdd(&acc[2], pacc);
}

// ------------------------------------------------------ decoder + likelihood
__global__ __launch_bounds__(256) void dec_kernel(
    const float* __restrict__ zsb, const float* __restrict__ xs,
    const float* __restrict__ dcW1, const float* __restrict__ dcb1,
    const float* __restrict__ dcW2, const float* __restrict__ dcb2,
    const float* __restrict__ dcW3, const float* __restrict__ dcb3,
    float* __restrict__ acc)
{
    __shared__ float w[4240];
    for (int i = threadIdx.x; i < 180; i += 256) w[i] = dcW1[i];
    if (threadIdx.x < 30) w[180 + threadIdx.x] = dcb1[threadIdx.x];
    for (int i = threadIdx.x; i < 900; i += 256) w[210 + i] = dcW2[i];
    if (threadIdx.x < 30) w[1110 + threadIdx.x] = dcb2[threadIdx.x];
    for (int i = threadIdx.x; i < 3000; i += 256) {
        int j2 = i / 100, j3 = i % 100;
        w[1140 + j3 * 30 + j2] = dcW3[i];
    }
    for (int i = threadIdx.x; i < 100; i += 256) w[4140 + i] = dcb3[i];
    __syncthreads();

    int gid = blockIdx.x * 256 + threadIdx.x;       // = t*Bn + b
    const float* zp = zsb + (size_t)gid * 6;
    float zv[6];
#pragma unroll
    for (int i = 0; i < 6; ++i) zv[i] = zp[i];

    float h1[30];
#pragma unroll
    for (int j = 0; j < 30; ++j) h1[j] = w[180 + j];
#pragma unroll
    for (int i = 0; i < 6; ++i) {
        float zi = zv[i];
#pragma unroll
        for (int j = 0; j < 30; ++j) h1[j] = fmaf(zi, w[i * 30 + j], h1[j]);
    }
#pragma unroll
    for (int j = 0; j < 30; ++j) h1[j] = sp_f(h1[j]);

    float h2[30];
#pragma unroll
    for (int j = 0; j < 30; ++j) h2[j] = w[1110 + j];
    for (int j1 = 0; j1 < 30; ++j1) {
        float hv = h1[j1];
#pragma unroll
        for (int j = 0; j < 30; ++j) h2[j] = fmaf(hv, w[210 + j1 * 30 + j], h2[j]);
    }
#pragma unroll
    for (int j = 0; j < 30; ++j) h2[j] = sp_f(h2[j]);

    const float* tg = xs + (size_t)gid * 150 + 100;   // xs[:,:,-1,:]
    float lpacc = 0.f;
    for (int ff = 0; ff < 50; ++ff) {
        float xm = w[4140 + ff], xl = w[4140 + 50 + ff];
#pragma unroll
        for (int j2 = 0; j2 < 30; ++j2) {
            xm = fmaf(h2[j2], w[1140 + ff * 30 + j2], xm);
            xl = fmaf(h2[j2], w[1140 + (50 + ff) * 30 + j2], xl);
        }
        float cl = clamp6(xl);
        float u = (tg[ff] - xm) * __expf(-cl);
        lpacc += -0.5f * u * u - cl - 0.91893853320467274f;
    }
#pragma unroll
    for (int mm = 1; mm <= 32; mm <<= 1) lpacc += __shfl_xor(lpacc, mm);
    __shared__ float red[4];
    if ((threadIdx.x & 63) == 0) red[threadIdx.x >> 6] = lpacc;
    __syncthreads();
    if (threadIdx.x == 0) atomicAdd(&acc[0], red[0] + red[1] + red[2] + red[3]);
}

__global__ void final_kernel(const float* __restrict__ acc, float* __restrict__ out)
{
    out[0] = acc[0] * (1.f / (float)Bn);
    out[1] = (acc[1] + acc[2]) * (1.f / (float)Bn);
}

// --------------------------------------------------------------------- launch
extern "C" void kernel_launch(void* const* d_in, const int* in_sizes, int n_in,
                              void* d_out, int out_size, void* d_ws, size_t ws_size,
                              hipStream_t stream)
{
    const float* xs   = (const float*)d_in[0];
    const float* ts   = (const float*)d_in[1];
    const float* eps0 = (const float*)d_in[2];
    const float* dW   = (const float*)d_in[3];
    const float* eW1  = (const float*)d_in[4];
    const float* eb1  = (const float*)d_in[5];
    const float* eW2  = (const float*)d_in[6];
    const float* eb2  = (const float*)d_in[7];
    const float* eW3  = (const float*)d_in[8];
    const float* eb3  = (const float*)d_in[9];
    const float* dcW1 = (const float*)d_in[10];
    const float* dcb1 = (const float*)d_in[11];
    const float* dcW2 = (const float*)d_in[12];
    const float* dcb2 = (const float*)d_in[13];
    const float* dcW3 = (const float*)d_in[14];
    const float* dcb3 = (const float*)d_in[15];
    const float* fW1  = (const float*)d_in[16];
    const float* fb1  = (const float*)d_in[17];
    const float* fW2  = (const float*)d_in[18];
    const float* fb2  = (const float*)d_in[19];
    const float* hW1  = (const float*)d_in[20];
    const float* hb1  = (const float*)d_in[21];
    const float* hW2  = (const float*)d_in[22];
    const float* hb2  = (const float*)d_in[23];
    const float* gW1  = (const float*)d_in[24];
    const float* gb1  = (const float*)d_in[25];
    const float* gW2  = (const float*)d_in[26];
    const float* gb2  = (const float*)d_in[27];
    const float* pm   = (const float*)d_in[28];
    const float* ps   = (const float*)d_in[29];

    float* ws  = (float*)d_ws;
    float* acc = ws;                    // [0]=S_lp, [1]=S_kl, [2]=S_path
    float* ctx = ws + 16;               // T*B*3 = 614400
    float* qm  = ctx + 614400;          // B*6
    float* qs  = qm + 12288;            // B*6
    float* zs  = qs + 12288;            // T*B*6 = 1228800
    float* out = (float*)d_out;

    hipMemsetAsync(acc, 0, 16 * sizeof(float), stream);
    enc_kernel<<<800, 256, 0, stream>>>(xs, eW1, eb1, eW2, eb2, eW3, eb3, ctx, qm, qs);
    z0kl_kernel<<<48, 256, 0, stream>>>(qm, qs, eps0, pm, ps, zs, acc);
    scan_kernel<<<512, 64, 0, stream>>>(ts, dW, fW1, fb1, fW2, fb2, hW1, hb1,
                                        hW2, hb2, gW1, gb1, gW2, gb2, ctx, zs, acc);
    dec_kernel<<<800, 256, 0, stream>>>(zs, xs, dcW1, dcb1, dcW2, dcb2, dcW3, dcb3, acc);
    final_kernel<<<1, 1, 0, stream>>>(acc, out);
}

// Round 4
// 336.633 us; speedup vs baseline: 1.9702x; 1.9702x over previous
//
#include <hip/hip_runtime.h>
#include <hip/hip_bf16.h>
#include <math.h>

#define Tn 100
#define Bn 2048

typedef int v2i __attribute__((ext_vector_type(2)));

__device__ __forceinline__ float sp_f(float x) {
    // jax.nn.softplus(x) = max(x,0) + log1p(exp(-|x|))
    float e = __expf(-fabsf(x));
    return fmaxf(x, 0.f) + __logf(1.f + e);
}
__device__ __forceinline__ float clamp6(float x) {
    return fminf(fmaxf(x, -6.f), 6.f);
}
// DPP cross-lane (pure VALU).
__device__ __forceinline__ float dpp_xor1(float x) {
    return __int_as_float(__builtin_amdgcn_mov_dpp(__float_as_int(x), 0xB1, 0xF, 0xF, 1));
}
__device__ __forceinline__ float dpp_xor2(float x) {
    return __int_as_float(__builtin_amdgcn_mov_dpp(__float_as_int(x), 0x4E, 0xF, 0xF, 1));
}
__device__ __forceinline__ float dpp_hmirror(float x) {   // == xor4 for quad-uniform
    return __int_as_float(__builtin_amdgcn_mov_dpp(__float_as_int(x), 0x141, 0xF, 0xF, 1));
}
__device__ __forceinline__ float dpp_ror8(float x) {      // == xor8 for 8-uniform
    return __int_as_float(__builtin_amdgcn_mov_dpp(__float_as_int(x), 0x128, 0xF, 0xF, 1));
}
template <int OFF>
__device__ __forceinline__ float swz(float x) {
    return __int_as_float(__builtin_amdgcn_ds_swizzle(__float_as_int(x), OFF));
}
// xor16 SUM stage: pair-sum of 16-rows; permlane16_swap(x,x) yields the two
// row-duplicated halves in some order -> r0+r1 is the xor16 sum either way.
__device__ __forceinline__ float xor16_sum(float x) {
#if __has_builtin(__builtin_amdgcn_permlane16_swap)
    v2i r = __builtin_amdgcn_permlane16_swap(__float_as_int(x), __float_as_int(x), false, false);
    return __int_as_float(r[0]) + __int_as_float(r[1]);
#else
    return x + swz<0x401F>(x);   // ds_swizzle xor16 within 32-groups
#endif
}
// value of lane (tid^32): direction-agnostic via r0+r1-own.
__device__ __forceinline__ float other_half(float x) {
#if __has_builtin(__builtin_amdgcn_permlane32_swap)
    v2i r = __builtin_amdgcn_permlane32_swap(__float_as_int(x), __float_as_int(x), false, false);
    return (__int_as_float(r[0]) + __int_as_float(r[1])) - x;
#else
    return __shfl_xor(x, 32);
#endif
}

// ---------------------------------------------------------------- encoder
__global__ __launch_bounds__(256) void enc_kernel(
    const float* __restrict__ xs,
    const float* __restrict__ eW1, const float* __restrict__ eb1,
    const float* __restrict__ eW2, const float* __restrict__ eb2,
    const float* __restrict__ eW3, const float* __restrict__ eb3,
    float* __restrict__ ctx, float* __restrict__ qm, float* __restrict__ qs)
{
    __shared__ float w[5925];
    for (int i = threadIdx.x; i < 4500; i += 256) w[i] = eW1[i];
    if (threadIdx.x < 30) w[4500 + threadIdx.x] = eb1[threadIdx.x];
    for (int i = threadIdx.x; i < 900; i += 256) w[4530 + i] = eW2[i];
    if (threadIdx.x < 30) w[5430 + threadIdx.x] = eb2[threadIdx.x];
    for (int i = threadIdx.x; i < 450; i += 256) w[5460 + i] = eW3[i];
    if (threadIdx.x < 15) w[5910 + threadIdx.x] = eb3[threadIdx.x];
    __syncthreads();

    int gid = blockIdx.x * 256 + threadIdx.x;          // = tt*Bn + b
    const float* x = xs + (size_t)gid * 150;

    float h1[30];
#pragma unroll
    for (int j = 0; j < 30; ++j) h1[j] = w[4500 + j];
    for (int i = 0; i < 150; i += 2) {
        float2 xv = *reinterpret_cast<const float2*>(x + i);
#pragma unroll
        for (int j = 0; j < 30; ++j) h1[j] = fmaf(xv.x, w[i * 30 + j], h1[j]);
#pragma unroll
        for (int j = 0; j < 30; ++j) h1[j] = fmaf(xv.y, w[(i + 1) * 30 + j], h1[j]);
    }
#pragma unroll
    for (int j = 0; j < 30; ++j) h1[j] = sp_f(h1[j]);

    float h2[30];
#pragma unroll
    for (int j = 0; j < 30; ++j) h2[j] = w[5430 + j];
    for (int j1 = 0; j1 < 30; ++j1) {
        float hv = h1[j1];
#pragma unroll
        for (int j = 0; j < 30; ++j) h2[j] = fmaf(hv, w[4530 + j1 * 30 + j], h2[j]);
    }
#pragma unroll
    for (int j = 0; j < 30; ++j) h2[j] = sp_f(h2[j]);

    float o12 = w[5910 + 12], o13 = w[5910 + 13], o14 = w[5910 + 14];
#pragma unroll
    for (int j2 = 0; j2 < 30; ++j2) {
        o12 = fmaf(h2[j2], w[5460 + j2 * 15 + 12], o12);
        o13 = fmaf(h2[j2], w[5460 + j2 * 15 + 13], o13);
        o14 = fmaf(h2[j2], w[5460 + j2 * 15 + 14], o14);
    }
    float* cp = ctx + (size_t)gid * 3;
    cp[0] = o12; cp[1] = o13; cp[2] = o14;

    if (blockIdx.x < 8) {   // tt == 0
        int b = gid;
        float o[12];
#pragma unroll
        for (int j3 = 0; j3 < 12; ++j3) o[j3] = w[5910 + j3];
#pragma unroll
        for (int j2 = 0; j2 < 30; ++j2) {
            float hv = h2[j2];
#pragma unroll
            for (int j3 = 0; j3 < 12; ++j3) o[j3] = fmaf(hv, w[5460 + j2 * 15 + j3], o[j3]);
        }
#pragma unroll
        for (int d = 0; d < 6; ++d) { qm[b * 6 + d] = o[d]; qs[b * 6 + d] = o[6 + d]; }
    }
}

// ---------------------------------------------------------- z0 + KL reduction
__global__ __launch_bounds__(256) void z0kl_kernel(
    const float* __restrict__ qm, const float* __restrict__ qs,
    const float* __restrict__ eps0, const float* __restrict__ pm,
    const float* __restrict__ ps, float* __restrict__ zsb, float* __restrict__ acc)
{
    int idx = blockIdx.x * 256 + threadIdx.x;   // < Bn*6
    int d = idx % 6;
    float m = qm[idx], lsq = qs[idx];
    float sq = __expf(clamp6(lsq));
    zsb[idx] = fmaf(sq, eps0[idx], m);          // zs[0][b][d]
    float spz = __expf(clamp6(ps[d]));
    float dm = m - pm[d];
    float kl = __logf(spz / sq) + (sq * sq + dm * dm) / (2.f * spz * spz) - 0.5f;
#pragma unroll
    for (int mm = 1; mm <= 32; mm <<= 1) kl += __shfl_xor(kl, mm);
    __shared__ float red[4];
    if ((threadIdx.x & 63) == 0) red[threadIdx.x >> 6] = kl;
    __syncthreads();
    if (threadIdx.x == 0) atomicAdd(&acc[1], red[0] + red[1] + red[2] + red[3]);
}

// ------------------------------------------------------------------- SDE scan
// 64 lanes per chain (1 wave = 1 chain), grid = 2048 (8 waves/CU, 2/SIMD).
// Lanes 0-29: f columns; lanes 32-61: h columns; g on 8-lane groups (dim=tid>>3).
// Per-lane weight set ~60 floats -> stays in VGPRs, no spill/remat.
__global__ __launch_bounds__(64, 2) void scan_kernel(
    const float* __restrict__ ts, const float* __restrict__ dWall,
    const float* __restrict__ fW1, const float* __restrict__ fb1,
    const float* __restrict__ fW2, const float* __restrict__ fb2,
    const float* __restrict__ hW1, const float* __restrict__ hb1,
    const float* __restrict__ hW2, const float* __restrict__ hb2,
    const float* __restrict__ gW1, const float* __restrict__ gb1,
    const float* __restrict__ gW2, const float* __restrict__ gb2,
    const float* __restrict__ ctx, float* __restrict__ zsb, float* __restrict__ acc)
{
    int tid = threadIdx.x;
    int b = blockIdx.x;
    bool lower = tid < 32;
    int j = tid & 31;
    int jc = (j < 30) ? j : 29;            // clamped (keeps loads in-bounds/finite)
    bool jvalid = (j < 30);

    // per-step record: [0..5]=dW, [6..8]=ctx(k+1), [9]=t, [10]=dt, [11]=pad
    __shared__ float sRec[99 * 12];

    for (int i = tid; i < 99 * 3; i += 64) {           // dW (float2 x3 per k)
        int k = i / 3, e = i % 3;
        float2 v = *(const float2*)(dWall + ((size_t)k * Bn + b) * 6 + e * 2);
        *(float2*)&sRec[k * 12 + e * 2] = v;
    }
    for (int i = tid; i < 99 * 3; i += 64) {           // ctx rows k+1
        int k = i / 3, e = i % 3;
        sRec[k * 12 + 6 + e] = ctx[((size_t)(k + 1) * Bn + b) * 3 + e];
    }
    for (int i = tid; i < 99; i += 64) {               // t, dt
        float t0 = ts[i], t1 = ts[i + 1];
        sRec[i * 12 + 9]  = t0;
        sRec[i * 12 + 10] = t1 - t0;
        sRec[i * 12 + 11] = 0.f;
    }

    // ---- per-lane weights (tiny) --------------------------------------
    float wl1[10], b1;
#pragma unroll
    for (int i = 0; i < 10; ++i)
        wl1[i] = lower ? fW1[i * 30 + jc] : (i < 7 ? hW1[i * 30 + jc] : 0.f);
    b1 = lower ? fb1[jc] : hb1[jc];
    float wl2[6];
#pragma unroll
    for (int d = 0; d < 6; ++d)
        wl2[d] = jvalid ? (lower ? fW2[jc * 6 + d] : hW2[jc * 6 + d]) : 0.f;
    float fb2v[6], hb2v[6];
#pragma unroll
    for (int d = 0; d < 6; ++d) { fb2v[d] = fb2[d]; hb2v[d] = hb2[d]; }

    int dL8 = tid >> 3;                    // 0..7; groups 0..5 are real dims
    int dL = (dL8 < 6) ? dL8 : 0;
    bool gv = (dL8 < 6);
    int s = tid & 7;
    float gwa[4], gwb[4], gw2v[4], gbb[4];
#pragma unroll
    for (int u = 0; u < 4; ++u) {
        int jj = s + 8 * u;
        bool ok = gv && (jj < 30);
        gwa[u]  = ok ? gW1[dL * 60 + jj] : 0.f;        // t coeff
        gwb[u]  = ok ? gW1[dL * 60 + 30 + jj] : 0.f;   // z coeff
        gw2v[u] = ok ? gW2[dL * 30 + jj] : 0.f;
        gbb[u]  = ok ? gb1[dL * 30 + jj] : 0.f;
    }
    float gb2v = gb2[dL];

    __syncthreads();

    float z[6];
#pragma unroll
    for (int d = 0; d < 6; ++d) z[d] = zsb[(size_t)b * 6 + d];
    float pacc = 0.f;

    for (int k = 0; k < Tn - 1; ++k) {
        float4 r0 = *(float4*)&sRec[k * 12];       // dw0..3
        float4 r1 = *(float4*)&sRec[k * 12 + 4];   // dw4,dw5,c0,c1
        float4 r2 = *(float4*)&sRec[k * 12 + 8];   // c2,t,dt,pad
        float t = r2.y, dt = r2.z;

        // own-dim z for g input
        float zq = z[0];
        zq = (dL == 1) ? z[1] : zq;
        zq = (dL == 2) ? z[2] : zq;
        zq = (dL == 3) ? z[3] : zq;
        zq = (dL == 4) ? z[4] : zq;
        zq = (dL == 5) ? z[5] : zq;

        // ---- g hidden: 4 units/lane, reduce over 8-lane group ---------
        float ga = 0.f;
#pragma unroll
        for (int u = 0; u < 4; ++u) {
            float pre = fmaf(t, gwa[u], gbb[u]);
            pre = fmaf(zq, gwb[u], pre);
            ga = fmaf(sp_f(pre), gw2v[u], ga);
        }
        ga += dpp_xor1(ga);
        ga += dpp_xor2(ga);
        ga += dpp_hmirror(ga);
        float gacc = ga + gb2v;
        float eg = __expf(-fabsf(gacc));
        float rden = __builtin_amdgcn_rcpf(1.f + eg);
        float gval = (gacc >= 0.f) ? rden : eg * rden;

        // ---- f/h hidden: one column per lane --------------------------
        float a = fmaf(t, wl1[0], b1);
#pragma unroll
        for (int i = 0; i < 6; ++i) a = fmaf(z[i], wl1[1 + i], a);
        a = fmaf(r1.z, wl1[7], a);
        a = fmaf(r1.w, wl1[8], a);
        a = fmaf(r2.x, wl1[9], a);
        float hid = sp_f(a);

        // ---- layer-2 partials + 32-lane butterfly (VALU only) ---------
        float pp[6];
#pragma unroll
        for (int d = 0; d < 6; ++d) pp[d] = hid * wl2[d];
#pragma unroll
        for (int d = 0; d < 6; ++d) pp[d] += dpp_xor1(pp[d]);
#pragma unroll
        for (int d = 0; d < 6; ++d) pp[d] += dpp_xor2(pp[d]);
#pragma unroll
        for (int d = 0; d < 6; ++d) pp[d] += dpp_hmirror(pp[d]);
#pragma unroll
        for (int d = 0; d < 6; ++d) pp[d] += dpp_ror8(pp[d]);
#pragma unroll
        for (int d = 0; d < 6; ++d) pp[d] = xor16_sum(pp[d]);
        // lower lanes now hold fsum[d], upper hold hsum[d]; exchange
        float fvv[6], hvv[6];
#pragma unroll
        for (int d = 0; d < 6; ++d) {
            float oth = other_half(pp[d]);
            float fsum = lower ? pp[d] : oth;
            float hsum = lower ? oth : pp[d];
            fvv[d] = fsum + fb2v[d];
            hvv[d] = hsum + hb2v[d];
        }

        // ---- broadcast g_d from lane 8d -------------------------------
        float gl[6];
#pragma unroll
        for (int d = 0; d < 6; ++d) gl[d] = __shfl(gval, d * 8, 64);

        // ---- path integrand (identical on all lanes) ------------------
        float s2 = 0.f;
#pragma unroll
        for (int d = 0; d < 6; ++d) {
            float u = (fvv[d] - hvv[d]) * __builtin_amdgcn_rcpf(gl[d]);
            s2 = fmaf(u, u, s2);
        }
        pacc = fmaf(0.5f * dt, s2, pacc);

        // ---- z update -------------------------------------------------
        float dwv[6] = { r0.x, r0.y, r0.z, r0.w, r1.x, r1.y };
#pragma unroll
        for (int d = 0; d < 6; ++d)
            z[d] = fmaf(gl[d], dwv[d], fmaf(fvv[d], dt, z[d]));

        if (tid == 0) {
            float* zp = zsb + ((size_t)(k + 1) * Bn + b) * 6;
            *(float2*)(zp)     = make_float2(z[0], z[1]);
            *(float2*)(zp + 2) = make_float2(z[2], z[3]);
            *(float2*)(zp + 4) = make_float2(z[4], z[5]);
        }
    }
    if (tid == 0) atomicAdd(&acc[2], pacc);   // pacc identical on all lanes
}

// ------------------------------------------------------ decoder + likelihood
__global__ __launch_bounds__(256) void dec_kernel(
    const float* __restrict__ zsb, const float* __restrict__ xs,
    const float* __restrict__ dcW1, const float* __restrict__ dcb1,
    const float* __restrict__ dcW2, const float* __restrict__ dcb2,
    const float* __restrict__ dcW3, const float* __restrict__ dcb3,
    float* __restrict__ acc)
{
    __shared__ float w[4240];
    for (int i = threadIdx.x; i < 180; i += 256) w[i] = dcW1[i];
    if (threadIdx.x < 30) w[180 + threadIdx.x] = dcb1[threadIdx.x];
    for (int i = threadIdx.x; i < 900; i += 256) w[210 + i] = dcW2[i];
    if (threadIdx.x < 30) w[1110 + threadIdx.x] = dcb2[threadIdx.x];
    for (int i = threadIdx.x; i < 3000; i += 256) {
        int j2 = i / 100, j3 = i % 100;
        w[1140 + j3 * 30 + j2] = dcW3[i];
    }
    for (int i = threadIdx.x; i < 100; i += 256) w[4140 + i] = dcb3[i];
    __syncthreads();

    int gid = blockIdx.x * 256 + threadIdx.x;       // = t*Bn + b
    const float* zp = zsb + (size_t)gid * 6;
    float zv[6];
#pragma unroll
    for (int i = 0; i < 6; ++i) zv[i] = zp[i];

    float h1[30];
#pragma unroll
    for (int j = 0; j < 30; ++j) h1[j] = w[180 + j];
#pragma unroll
    for (int i = 0; i < 6; ++i) {
        float zi = zv[i];
#pragma unroll
        for (int j = 0; j < 30; ++j) h1[j] = fmaf(zi, w[i * 30 + j], h1[j]);
    }
#pragma unroll
    for (int j = 0; j < 30; ++j) h1[j] = sp_f(h1[j]);

    float h2[30];
#pragma unroll
    for (int j = 0; j < 30; ++j) h2[j] = w[1110 + j];
    for (int j1 = 0; j1 < 30; ++j1) {
        float hv = h1[j1];
#pragma unroll
        for (int j = 0; j < 30; ++j) h2[j] = fmaf(hv, w[210 + j1 * 30 + j], h2[j]);
    }
#pragma unroll
    for (int j = 0; j < 30; ++j) h2[j] = sp_f(h2[j]);

    const float* tg = xs + (size_t)gid * 150 + 100;   // xs[:,:,-1,:]
    float lpacc = 0.f;
    for (int ff = 0; ff < 50; ++ff) {
        float xm = w[4140 + ff], xl = w[4140 + 50 + ff];
#pragma unroll
        for (int j2 = 0; j2 < 30; ++j2) {
            xm = fmaf(h2[j2], w[1140 + ff * 30 + j2], xm);
            xl = fmaf(h2[j2], w[1140 + (50 + ff) * 30 + j2], xl);
        }
        float cl = clamp6(xl);
        float u = (tg[ff] - xm) * __expf(-cl);
        lpacc += -0.5f * u * u - cl - 0.91893853320467274f;
    }
#pragma unroll
    for (int mm = 1; mm <= 32; mm <<= 1) lpacc += __shfl_xor(lpacc, mm);
    __shared__ float red[4];
    if ((threadIdx.x & 63) == 0) red[threadIdx.x >> 6] = lpacc;
    __syncthreads();
    if (threadIdx.x == 0) atomicAdd(&acc[0], red[0] + red[1] + red[2] + red[3]);
}

__global__ void final_kernel(const float* __restrict__ acc, float* __restrict__ out)
{
    out[0] = acc[0] * (1.f / (float)Bn);
    out[1] = (acc[1] + acc[2]) * (1.f / (float)Bn);
}

// --------------------------------------------------------------------- launch
extern "C" void kernel_launch(void* const* d_in, const int* in_sizes, int n_in,
                              void* d_out, int out_size, void* d_ws, size_t ws_size,
                              hipStream_t stream)
{
    const float* xs   = (const float*)d_in[0];
    const float* ts   = (const float*)d_in[1];
    const float* eps0 = (const float*)d_in[2];
    const float* dW   = (const float*)d_in[3];
    const float* eW1  = (const float*)d_in[4];
    const float* eb1  = (const float*)d_in[5];
    const float* eW2  = (const float*)d_in[6];
    const float* eb2  = (const float*)d_in[7];
    const float* eW3  = (const float*)d_in[8];
    const float* eb3  = (const float*)d_in[9];
    const float* dcW1 = (const float*)d_in[10];
    const float* dcb1 = (const float*)d_in[11];
    const float* dcW2 = (const float*)d_in[12];
    const float* dcb2 = (const float*)d_in[13];
    const float* dcW3 = (const float*)d_in[14];
    const float* dcb3 = (const float*)d_in[15];
    const float* fW1  = (const float*)d_in[16];
    const float* fb1  = (const float*)d_in[17];
    const float* fW2  = (const float*)d_in[18];
    const float* fb2  = (const float*)d_in[19];
    const float* hW1  = (const float*)d_in[20];
    const float* hb1  = (const float*)d_in[21];
    const float* hW2  = (const float*)d_in[22];
    const float* hb2  = (const float*)d_in[23];
    const float* gW1  = (const float*)d_in[24];
    const float* gb1  = (const float*)d_in[25];
    const float* gW2  = (const float*)d_in[26];
    const float* gb2  = (const float*)d_in[27];
    const float* pm   = (const float*)d_in[28];
    const float* ps   = (const float*)d_in[29];

    float* ws  = (float*)d_ws;
    float* acc = ws;                    // [0]=S_lp, [1]=S_kl, [2]=S_path
    float* ctx = ws + 16;               // T*B*3 = 614400
    float* qm  = ctx + 614400;          // B*6
    float* qs  = qm + 12288;            // B*6
    float* zs  = qs + 12288;            // T*B*6 = 1228800
    float* out = (float*)d_out;

    hipMemsetAsync(acc, 0, 16 * sizeof(float), stream);
    enc_kernel<<<800, 256, 0, stream>>>(xs, eW1, eb1, eW2, eb2, eW3, eb3, ctx, qm, qs);
    z0kl_kernel<<<48, 256, 0, stream>>>(qm, qs, eps0, pm, ps, zs, acc);
    scan_kernel<<<2048, 64, 0, stream>>>(ts, dW, fW1, fb1, fW2, fb2, hW1, hb1,
                                         hW2, hb2, gW1, gb1, gW2, gb2, ctx, zs, acc);
    dec_kernel<<<800, 256, 0, stream>>>(zs, xs, dcW1, dcb1, dcW2, dcb2, dcW3, dcb3, acc);
    final_kernel<<<1, 1, 0, stream>>>(acc, out);
}

// Round 5
// 313.697 us; speedup vs baseline: 2.1142x; 1.0731x over previous
//
#include <hip/hip_runtime.h>
#include <hip/hip_bf16.h>
#include <math.h>

#define Tn 100
#define Bn 2048

typedef int v2i __attribute__((ext_vector_type(2)));

__device__ __forceinline__ float sp_f(float x) {
    // jax.nn.softplus(x) = max(x,0) + log1p(exp(-|x|))
    float e = __expf(-fabsf(x));
    return fmaxf(x, 0.f) + __logf(1.f + e);
}
__device__ __forceinline__ float clamp6(float x) {
    return fminf(fmaxf(x, -6.f), 6.f);
}
// DPP cross-lane (pure VALU).
__device__ __forceinline__ float dpp_xor1(float x) {
    return __int_as_float(__builtin_amdgcn_mov_dpp(__float_as_int(x), 0xB1, 0xF, 0xF, 1));
}
__device__ __forceinline__ float dpp_xor2(float x) {
    return __int_as_float(__builtin_amdgcn_mov_dpp(__float_as_int(x), 0x4E, 0xF, 0xF, 1));
}
__device__ __forceinline__ float dpp_hmirror(float x) {   // == xor4 for quad-uniform
    return __int_as_float(__builtin_amdgcn_mov_dpp(__float_as_int(x), 0x141, 0xF, 0xF, 1));
}
__device__ __forceinline__ float dpp_ror8(float x) {      // == xor8 for 8-uniform
    return __int_as_float(__builtin_amdgcn_mov_dpp(__float_as_int(x), 0x128, 0xF, 0xF, 1));
}
template <int OFF>
__device__ __forceinline__ float swz(float x) {
    return __int_as_float(__builtin_amdgcn_ds_swizzle(__float_as_int(x), OFF));
}
__device__ __forceinline__ float xor16_sum(float x) {
#if __has_builtin(__builtin_amdgcn_permlane16_swap)
    v2i r = __builtin_amdgcn_permlane16_swap(__float_as_int(x), __float_as_int(x), false, false);
    return __int_as_float(r[0]) + __int_as_float(r[1]);
#else
    return x + swz<0x401F>(x);
#endif
}
__device__ __forceinline__ float other_half(float x) {
#if __has_builtin(__builtin_amdgcn_permlane32_swap)
    v2i r = __builtin_amdgcn_permlane32_swap(__float_as_int(x), __float_as_int(x), false, false);
    return (__int_as_float(r[0]) + __int_as_float(r[1])) - x;
#else
    return __shfl_xor(x, 32);
#endif
}

// ---------------------------------------------------------------- encoder
// Software-pipelined: chunks of 10 features, A/B ping-pong register buffers.
#define ENC_LOAD(buf, base)                                                   \
    _Pragma("unroll")                                                         \
    for (int i = 0; i < 5; ++i) buf[i] = *(const float2*)(x + (base) + 2 * i);
#define ENC_COMP(buf, base)                                                   \
    _Pragma("unroll")                                                         \
    for (int i = 0; i < 5; ++i) {                                             \
        float vx = buf[i].x, vy = buf[i].y;                                   \
        const float* wp = &w[(base + 2 * i) * 30];                            \
        _Pragma("unroll")                                                     \
        for (int j = 0; j < 30; ++j) h1[j] = fmaf(vx, wp[j], h1[j]);          \
        _Pragma("unroll")                                                     \
        for (int j = 0; j < 30; ++j) h1[j] = fmaf(vy, wp[30 + j], h1[j]);     \
    }

__global__ __launch_bounds__(256) void enc_kernel(
    const float* __restrict__ xs,
    const float* __restrict__ eW1, const float* __restrict__ eb1,
    const float* __restrict__ eW2, const float* __restrict__ eb2,
    const float* __restrict__ eW3, const float* __restrict__ eb3,
    float* __restrict__ ctx, float* __restrict__ qm, float* __restrict__ qs)
{
    __shared__ float w[5925];
    for (int i = threadIdx.x; i < 4500; i += 256) w[i] = eW1[i];
    if (threadIdx.x < 30) w[4500 + threadIdx.x] = eb1[threadIdx.x];
    for (int i = threadIdx.x; i < 900; i += 256) w[4530 + i] = eW2[i];
    if (threadIdx.x < 30) w[5430 + threadIdx.x] = eb2[threadIdx.x];
    for (int i = threadIdx.x; i < 450; i += 256) w[5460 + i] = eW3[i];
    if (threadIdx.x < 15) w[5910 + threadIdx.x] = eb3[threadIdx.x];
    __syncthreads();

    int gid = blockIdx.x * 256 + threadIdx.x;          // = tt*Bn + b
    const float* x = xs + (size_t)gid * 150;

    float h1[30];
#pragma unroll
    for (int j = 0; j < 30; ++j) h1[j] = w[4500 + j];

    float2 A[5], Bf[5];
    ENC_LOAD(A, 0)
    ENC_LOAD(Bf, 10)
    int fb = 0;
#pragma unroll 1
    for (int it = 0; it < 6; ++it) {
        ENC_COMP(A, fb)
        ENC_LOAD(A, fb + 20)
        ENC_COMP(Bf, fb + 10)
        ENC_LOAD(Bf, fb + 30)
        fb += 20;
    }
    // fb = 120; A = features 120..129, Bf = 130..139
    ENC_COMP(A, 120)
    ENC_LOAD(A, 140)
    ENC_COMP(Bf, 130)
    ENC_COMP(A, 140)

#pragma unroll
    for (int j = 0; j < 30; ++j) h1[j] = sp_f(h1[j]);

    float h2[30];
#pragma unroll
    for (int j = 0; j < 30; ++j) h2[j] = w[5430 + j];
    for (int j1 = 0; j1 < 30; ++j1) {
        float hv = h1[j1];
#pragma unroll
        for (int j = 0; j < 30; ++j) h2[j] = fmaf(hv, w[4530 + j1 * 30 + j], h2[j]);
    }
#pragma unroll
    for (int j = 0; j < 30; ++j) h2[j] = sp_f(h2[j]);

    float o12 = w[5910 + 12], o13 = w[5910 + 13], o14 = w[5910 + 14];
#pragma unroll
    for (int j2 = 0; j2 < 30; ++j2) {
        o12 = fmaf(h2[j2], w[5460 + j2 * 15 + 12], o12);
        o13 = fmaf(h2[j2], w[5460 + j2 * 15 + 13], o13);
        o14 = fmaf(h2[j2], w[5460 + j2 * 15 + 14], o14);
    }
    float* cp = ctx + (size_t)gid * 3;
    cp[0] = o12; cp[1] = o13; cp[2] = o14;

    if (blockIdx.x < 8) {   // tt == 0
        int b = gid;
        float o[12];
#pragma unroll
        for (int j3 = 0; j3 < 12; ++j3) o[j3] = w[5910 + j3];
#pragma unroll
        for (int j2 = 0; j2 < 30; ++j2) {
            float hv = h2[j2];
#pragma unroll
            for (int j3 = 0; j3 < 12; ++j3) o[j3] = fmaf(hv, w[5460 + j2 * 15 + j3], o[j3]);
        }
#pragma unroll
        for (int d = 0; d < 6; ++d) { qm[b * 6 + d] = o[d]; qs[b * 6 + d] = o[6 + d]; }
    }
}

// ---------------------------------------------------------- z0 + KL reduction
__global__ __launch_bounds__(256) void z0kl_kernel(
    const float* __restrict__ qm, const float* __restrict__ qs,
    const float* __restrict__ eps0, const float* __restrict__ pm,
    const float* __restrict__ ps, float* __restrict__ zsb, float* __restrict__ acc)
{
    int idx = blockIdx.x * 256 + threadIdx.x;   // < Bn*6
    int d = idx % 6;
    float m = qm[idx], lsq = qs[idx];
    float sq = __expf(clamp6(lsq));
    zsb[idx] = fmaf(sq, eps0[idx], m);          // zs[0][b][d]
    float spz = __expf(clamp6(ps[d]));
    float dm = m - pm[d];
    float kl = __logf(spz / sq) + (sq * sq + dm * dm) / (2.f * spz * spz) - 0.5f;
#pragma unroll
    for (int mm = 1; mm <= 32; mm <<= 1) kl += __shfl_xor(kl, mm);
    __shared__ float red[4];
    if ((threadIdx.x & 63) == 0) red[threadIdx.x >> 6] = kl;
    __syncthreads();
    if (threadIdx.x == 0) atomicAdd(&acc[1], red[0] + red[1] + red[2] + red[3]);
}

// ------------------------------------------------------------------- SDE scan
// 64 lanes per chain (1 wave = 1 chain), grid = 2048 (8 waves/CU, 2/SIMD).
__global__ __launch_bounds__(64, 2) void scan_kernel(
    const float* __restrict__ ts, const float* __restrict__ dWall,
    const float* __restrict__ fW1, const float* __restrict__ fb1,
    const float* __restrict__ fW2, const float* __restrict__ fb2,
    const float* __restrict__ hW1, const float* __restrict__ hb1,
    const float* __restrict__ hW2, const float* __restrict__ hb2,
    const float* __restrict__ gW1, const float* __restrict__ gb1,
    const float* __restrict__ gW2, const float* __restrict__ gb2,
    const float* __restrict__ ctx, float* __restrict__ zsb, float* __restrict__ acc)
{
    int tid = threadIdx.x;
    int b = blockIdx.x;
    bool lower = tid < 32;
    int j = tid & 31;
    int jc = (j < 30) ? j : 29;            // clamped (keeps loads in-bounds/finite)
    bool jvalid = (j < 30);

    // per-step record: [0..5]=dW, [6..8]=ctx(k+1), [9]=t, [10]=dt, [11]=pad
    __shared__ float sRec[99 * 12];

    for (int i = tid; i < 99 * 3; i += 64) {           // dW (float2 x3 per k)
        int k = i / 3, e = i % 3;
        float2 v = *(const float2*)(dWall + ((size_t)k * Bn + b) * 6 + e * 2);
        *(float2*)&sRec[k * 12 + e * 2] = v;
    }
    for (int i = tid; i < 99 * 3; i += 64) {           // ctx rows k+1
        int k = i / 3, e = i % 3;
        sRec[k * 12 + 6 + e] = ctx[((size_t)(k + 1) * Bn + b) * 3 + e];
    }
    for (int i = tid; i < 99; i += 64) {               // t, dt
        float t0 = ts[i], t1 = ts[i + 1];
        sRec[i * 12 + 9]  = t0;
        sRec[i * 12 + 10] = t1 - t0;
        sRec[i * 12 + 11] = 0.f;
    }

    // ---- per-lane weights (tiny) --------------------------------------
    float wl1[10], b1;
#pragma unroll
    for (int i = 0; i < 10; ++i)
        wl1[i] = lower ? fW1[i * 30 + jc] : (i < 7 ? hW1[i * 30 + jc] : 0.f);
    b1 = lower ? fb1[jc] : hb1[jc];
    float wl2[6];
#pragma unroll
    for (int d = 0; d < 6; ++d)
        wl2[d] = jvalid ? (lower ? fW2[jc * 6 + d] : hW2[jc * 6 + d]) : 0.f;
    float fb2v[6], hb2v[6];
#pragma unroll
    for (int d = 0; d < 6; ++d) { fb2v[d] = fb2[d]; hb2v[d] = hb2[d]; }

    int dL8 = tid >> 3;                    // 0..7; groups 0..5 are real dims
    int dL = (dL8 < 6) ? dL8 : 0;
    bool gv = (dL8 < 6);
    int s = tid & 7;
    float gwa[4], gwb[4], gw2v[4], gbb[4];
#pragma unroll
    for (int u = 0; u < 4; ++u) {
        int jj = s + 8 * u;
        bool ok = gv && (jj < 30);
        gwa[u]  = ok ? gW1[dL * 60 + jj] : 0.f;        // t coeff
        gwb[u]  = ok ? gW1[dL * 60 + 30 + jj] : 0.f;   // z coeff
        gw2v[u] = ok ? gW2[dL * 30 + jj] : 0.f;
        gbb[u]  = ok ? gb1[dL * 30 + jj] : 0.f;
    }
    float gb2v = gb2[dL];

    __syncthreads();

    float z[6];
#pragma unroll
    for (int d = 0; d < 6; ++d) z[d] = zsb[(size_t)b * 6 + d];
    float pacc = 0.f;

    for (int k = 0; k < Tn - 1; ++k) {
        float4 r0 = *(float4*)&sRec[k * 12];       // dw0..3
        float4 r1 = *(float4*)&sRec[k * 12 + 4];   // dw4,dw5,c0,c1
        float4 r2 = *(float4*)&sRec[k * 12 + 8];   // c2,t,dt,pad
        float t = r2.y, dt = r2.z;

        // own-dim z for g input
        float zq = z[0];
        zq = (dL == 1) ? z[1] : zq;
        zq = (dL == 2) ? z[2] : zq;
        zq = (dL == 3) ? z[3] : zq;
        zq = (dL == 4) ? z[4] : zq;
        zq = (dL == 5) ? z[5] : zq;

        // ---- g hidden: 4 units/lane, reduce over 8-lane group ---------
        float ga = 0.f;
#pragma unroll
        for (int u = 0; u < 4; ++u) {
            float pre = fmaf(t, gwa[u], gbb[u]);
            pre = fmaf(zq, gwb[u], pre);
            ga = fmaf(sp_f(pre), gw2v[u], ga);
        }
        ga += dpp_xor1(ga);
        ga += dpp_xor2(ga);
        ga += dpp_hmirror(ga);
        float gacc = ga + gb2v;
        float eg = __expf(-fabsf(gacc));
        float rden = __builtin_amdgcn_rcpf(1.f + eg);
        float gval = (gacc >= 0.f) ? rden : eg * rden;

        // ---- f/h hidden: one column per lane --------------------------
        float a = fmaf(t, wl1[0], b1);
#pragma unroll
        for (int i = 0; i < 6; ++i) a = fmaf(z[i], wl1[1 + i], a);
        a = fmaf(r1.z, wl1[7], a);
        a = fmaf(r1.w, wl1[8], a);
        a = fmaf(r2.x, wl1[9], a);
        float hid = sp_f(a);

        // ---- layer-2 partials + 32-lane butterfly (VALU only) ---------
        float pp[6];
#pragma unroll
        for (int d = 0; d < 6; ++d) pp[d] = hid * wl2[d];
#pragma unroll
        for (int d = 0; d < 6; ++d) pp[d] += dpp_xor1(pp[d]);
#pragma unroll
        for (int d = 0; d < 6; ++d) pp[d] += dpp_xor2(pp[d]);
#pragma unroll
        for (int d = 0; d < 6; ++d) pp[d] += dpp_hmirror(pp[d]);
#pragma unroll
        for (int d = 0; d < 6; ++d) pp[d] += dpp_ror8(pp[d]);
#pragma unroll
        for (int d = 0; d < 6; ++d) pp[d] = xor16_sum(pp[d]);
        // lower lanes now hold fsum[d], upper hold hsum[d]; exchange
        float fvv[6], hvv[6];
#pragma unroll
        for (int d = 0; d < 6; ++d) {
            float oth = other_half(pp[d]);
            float fsum = lower ? pp[d] : oth;
            float hsum = lower ? oth : pp[d];
            fvv[d] = fsum + fb2v[d];
            hvv[d] = hsum + hb2v[d];
        }

        // ---- broadcast g_d from lane 8d -------------------------------
        float gl[6];
#pragma unroll
        for (int d = 0; d < 6; ++d) gl[d] = __shfl(gval, d * 8, 64);

        // ---- path integrand (identical on all lanes) ------------------
        float s2 = 0.f;
#pragma unroll
        for (int d = 0; d < 6; ++d) {
            float u = (fvv[d] - hvv[d]) * __builtin_amdgcn_rcpf(gl[d]);
            s2 = fmaf(u, u, s2);
        }
        pacc = fmaf(0.5f * dt, s2, pacc);

        // ---- z update -------------------------------------------------
        float dwv[6] = { r0.x, r0.y, r0.z, r0.w, r1.x, r1.y };
#pragma unroll
        for (int d = 0; d < 6; ++d)
            z[d] = fmaf(gl[d], dwv[d], fmaf(fvv[d], dt, z[d]));

        if (tid == 0) {
            float* zp = zsb + ((size_t)(k + 1) * Bn + b) * 6;
            *(float2*)(zp)     = make_float2(z[0], z[1]);
            *(float2*)(zp + 2) = make_float2(z[2], z[3]);
            *(float2*)(zp + 4) = make_float2(z[4], z[5]);
        }
    }
    if (tid == 0) atomicAdd(&acc[2], pacc);   // pacc identical on all lanes
}

// ------------------------------------------------------ decoder + likelihood
__global__ __launch_bounds__(256) void dec_kernel(
    const float* __restrict__ zsb, const float* __restrict__ xs,
    const float* __restrict__ dcW1, const float* __restrict__ dcb1,
    const float* __restrict__ dcW2, const float* __restrict__ dcb2,
    const float* __restrict__ dcW3, const float* __restrict__ dcb3,
    float* __restrict__ acc)
{
    __shared__ float w[4240];
    for (int i = threadIdx.x; i < 180; i += 256) w[i] = dcW1[i];
    if (threadIdx.x < 30) w[180 + threadIdx.x] = dcb1[threadIdx.x];
    for (int i = threadIdx.x; i < 900; i += 256) w[210 + i] = dcW2[i];
    if (threadIdx.x < 30) w[1110 + threadIdx.x] = dcb2[threadIdx.x];
    for (int i = threadIdx.x; i < 3000; i += 256) {
        int j2 = i / 100, j3 = i % 100;
        w[1140 + j3 * 30 + j2] = dcW3[i];
    }
    for (int i = threadIdx.x; i < 100; i += 256) w[4140 + i] = dcb3[i];
    __syncthreads();

    int gid = blockIdx.x * 256 + threadIdx.x;       // = t*Bn + b

    // prefetch likelihood targets (50 floats) into registers up front;
    // the 1080-FMA MLP below hides the HBM latency.
    const float* tg = xs + (size_t)gid * 150 + 100;   // xs[:,:,-1,:]
    float2 tgv[25];
#pragma unroll
    for (int i = 0; i < 25; ++i) tgv[i] = *(const float2*)(tg + 2 * i);

    const float* zp = zsb + (size_t)gid * 6;
    float zv[6];
#pragma unroll
    for (int i = 0; i < 3; ++i) {
        float2 zv2 = *(const float2*)(zp + 2 * i);
        zv[2 * i] = zv2.x; zv[2 * i + 1] = zv2.y;
    }

    float h1[30];
#pragma unroll
    for (int j = 0; j < 30; ++j) h1[j] = w[180 + j];
#pragma unroll
    for (int i = 0; i < 6; ++i) {
        float zi = zv[i];
#pragma unroll
        for (int j = 0; j < 30; ++j) h1[j] = fmaf(zi, w[i * 30 + j], h1[j]);
    }
#pragma unroll
    for (int j = 0; j < 30; ++j) h1[j] = sp_f(h1[j]);

    float h2[30];
#pragma unroll
    for (int j = 0; j < 30; ++j) h2[j] = w[1110 + j];
    for (int j1 = 0; j1 < 30; ++j1) {
        float hv = h1[j1];
#pragma unroll
        for (int j = 0; j < 30; ++j) h2[j] = fmaf(hv, w[210 + j1 * 30 + j], h2[j]);
    }
#pragma unroll
    for (int j = 0; j < 30; ++j) h2[j] = sp_f(h2[j]);

    float lpacc = 0.f;
#pragma unroll
    for (int ff = 0; ff < 50; ++ff) {
        float xm = w[4140 + ff], xl = w[4140 + 50 + ff];
#pragma unroll
        for (int j2 = 0; j2 < 30; ++j2) {
            xm = fmaf(h2[j2], w[1140 + ff * 30 + j2], xm);
            xl = fmaf(h2[j2], w[1140 + (50 + ff) * 30 + j2], xl);
        }
        float cl = clamp6(xl);
        float tv = (ff & 1) ? tgv[ff >> 1].y : tgv[ff >> 1].x;
        float u = (tv - xm) * __expf(-cl);
        lpacc += -0.5f * u * u - cl - 0.91893853320467274f;
    }
#pragma unroll
    for (int mm = 1; mm <= 32; mm <<= 1) lpacc += __shfl_xor(lpacc, mm);
    __shared__ float red[4];
    if ((threadIdx.x & 63) == 0) red[threadIdx.x >> 6] = lpacc;
    __syncthreads();
    if (threadIdx.x == 0) atomicAdd(&acc[0], red[0] + red[1] + red[2] + red[3]);
}

__global__ void final_kernel(const float* __restrict__ acc, float* __restrict__ out)
{
    out[0] = acc[0] * (1.f / (float)Bn);
    out[1] = (acc[1] + acc[2]) * (1.f / (float)Bn);
}

// --------------------------------------------------------------------- launch
extern "C" void kernel_launch(void* const* d_in, const int* in_sizes, int n_in,
                              void* d_out, int out_size, void* d_ws, size_t ws_size,
                              hipStream_t stream)
{
    const float* xs   = (const float*)d_in[0];
    const float* ts   = (const float*)d_in[1];
    const float* eps0 = (const float*)d_in[2];
    const float* dW   = (const float*)d_in[3];
    const float* eW1  = (const float*)d_in[4];
    const float* eb1  = (const float*)d_in[5];
    const float* eW2  = (const float*)d_in[6];
    const float* eb2  = (const float*)d_in[7];
    const float* eW3  = (const float*)d_in[8];
    const float* eb3  = (const float*)d_in[9];
    const float* dcW1 = (const float*)d_in[10];
    const float* dcb1 = (const float*)d_in[11];
    const float* dcW2 = (const float*)d_in[12];
    const float* dcb2 = (const float*)d_in[13];
    const float* dcW3 = (const float*)d_in[14];
    const float* dcb3 = (const float*)d_in[15];
    const float* fW1  = (const float*)d_in[16];
    const float* fb1  = (const float*)d_in[17];
    const float* fW2  = (const float*)d_in[18];
    const float* fb2  = (const float*)d_in[19];
    const float* hW1  = (const float*)d_in[20];
    const float* hb1  = (const float*)d_in[21];
    const float* hW2  = (const float*)d_in[22];
    const float* hb2  = (const float*)d_in[23];
    const float* gW1  = (const float*)d_in[24];
    const float* gb1  = (const float*)d_in[25];
    const float* gW2  = (const float*)d_in[26];
    const float* gb2  = (const float*)d_in[27];
    const float* pm   = (const float*)d_in[28];
    const float* ps   = (const float*)d_in[29];

    float* ws  = (float*)d_ws;
    float* acc = ws;                    // [0]=S_lp, [1]=S_kl, [2]=S_path
    float* ctx = ws + 16;               // T*B*3 = 614400
    float* qm  = ctx + 614400;          // B*6
    float* qs  = qm + 12288;            // B*6
    float* zs  = qs + 12288;            // T*B*6 = 1228800
    float* out = (float*)d_out;

    hipMemsetAsync(acc, 0, 16 * sizeof(float), stream);
    enc_kernel<<<800, 256, 0, stream>>>(xs, eW1, eb1, eW2, eb2, eW3, eb3, ctx, qm, qs);
    z0kl_kernel<<<48, 256, 0, stream>>>(qm, qs, eps0, pm, ps, zs, acc);
    scan_kernel<<<2048, 64, 0, stream>>>(ts, dW, fW1, fb1, fW2, fb2, hW1, hb1,
                                         hW2, hb2, gW1, gb1, gW2, gb2, ctx, zs, acc);
    dec_kernel<<<800, 256, 0, stream>>>(zs, xs, dcW1, dcb1, dcW2, dcb2, dcW3, dcb3, acc);
    final_kernel<<<1, 1, 0, stream>>>(acc, out);
}

// Round 6
// 287.064 us; speedup vs baseline: 2.3104x; 1.0928x over previous
//
#include <hip/hip_runtime.h>
#include <hip/hip_bf16.h>
#include <math.h>

#define Tn 100
#define Bn 2048

typedef int v2i __attribute__((ext_vector_type(2)));

__device__ __forceinline__ float sp_f(float x) {
    // jax.nn.softplus(x) = max(x,0) + log1p(exp(-|x|))
    float e = __expf(-fabsf(x));
    return fmaxf(x, 0.f) + __logf(1.f + e);
}
__device__ __forceinline__ float clamp6(float x) {
    return fminf(fmaxf(x, -6.f), 6.f);
}
// DPP cross-lane (pure VALU).
__device__ __forceinline__ float dpp_xor1(float x) {
    return __int_as_float(__builtin_amdgcn_mov_dpp(__float_as_int(x), 0xB1, 0xF, 0xF, 1));
}
__device__ __forceinline__ float dpp_xor2(float x) {
    return __int_as_float(__builtin_amdgcn_mov_dpp(__float_as_int(x), 0x4E, 0xF, 0xF, 1));
}
__device__ __forceinline__ float dpp_hmirror(float x) {   // == xor4 for quad-uniform
    return __int_as_float(__builtin_amdgcn_mov_dpp(__float_as_int(x), 0x141, 0xF, 0xF, 1));
}
__device__ __forceinline__ float dpp_ror8(float x) {      // == xor8 for 8-uniform
    return __int_as_float(__builtin_amdgcn_mov_dpp(__float_as_int(x), 0x128, 0xF, 0xF, 1));
}
template <int OFF>
__device__ __forceinline__ float swz(float x) {
    return __int_as_float(__builtin_amdgcn_ds_swizzle(__float_as_int(x), OFF));
}
__device__ __forceinline__ float xor16_sum(float x) {
#if __has_builtin(__builtin_amdgcn_permlane16_swap)
    v2i r = __builtin_amdgcn_permlane16_swap(__float_as_int(x), __float_as_int(x), false, false);
    return __int_as_float(r[0]) + __int_as_float(r[1]);
#else
    return x + swz<0x401F>(x);
#endif
}
__device__ __forceinline__ float other_half(float x) {
#if __has_builtin(__builtin_amdgcn_permlane32_swap)
    v2i r = __builtin_amdgcn_permlane32_swap(__float_as_int(x), __float_as_int(x), false, false);
    return (__int_as_float(r[0]) + __int_as_float(r[1])) - x;
#else
    return __shfl_xor(x, 32);
#endif
}

// ---------------------------------------------------------------- encoder
// Software-pipelined: chunks of 10 features, A/B ping-pong register buffers.
#define ENC_LOAD(buf, base)                                                   \
    _Pragma("unroll")                                                         \
    for (int i = 0; i < 5; ++i) buf[i] = *(const float2*)(x + (base) + 2 * i);
#define ENC_COMP(buf, base)                                                   \
    _Pragma("unroll")                                                         \
    for (int i = 0; i < 5; ++i) {                                             \
        float vx = buf[i].x, vy = buf[i].y;                                   \
        const float* wp = &w[(base + 2 * i) * 30];                            \
        _Pragma("unroll")                                                     \
        for (int j = 0; j < 30; ++j) h1[j] = fmaf(vx, wp[j], h1[j]);          \
        _Pragma("unroll")                                                     \
        for (int j = 0; j < 30; ++j) h1[j] = fmaf(vy, wp[30 + j], h1[j]);     \
    }

__global__ __launch_bounds__(256) void enc_kernel(
    const float* __restrict__ xs,
    const float* __restrict__ eW1, const float* __restrict__ eb1,
    const float* __restrict__ eW2, const float* __restrict__ eb2,
    const float* __restrict__ eW3, const float* __restrict__ eb3,
    float* __restrict__ ctx, float* __restrict__ qm, float* __restrict__ qs)
{
    __shared__ float w[5925];
    for (int i = threadIdx.x; i < 4500; i += 256) w[i] = eW1[i];
    if (threadIdx.x < 30) w[4500 + threadIdx.x] = eb1[threadIdx.x];
    for (int i = threadIdx.x; i < 900; i += 256) w[4530 + i] = eW2[i];
    if (threadIdx.x < 30) w[5430 + threadIdx.x] = eb2[threadIdx.x];
    for (int i = threadIdx.x; i < 450; i += 256) w[5460 + i] = eW3[i];
    if (threadIdx.x < 15) w[5910 + threadIdx.x] = eb3[threadIdx.x];
    __syncthreads();

    int gid = blockIdx.x * 256 + threadIdx.x;          // = tt*Bn + b
    const float* x = xs + (size_t)gid * 150;

    float h1[30];
#pragma unroll
    for (int j = 0; j < 30; ++j) h1[j] = w[4500 + j];

    float2 A[5], Bf[5];
    ENC_LOAD(A, 0)
    ENC_LOAD(Bf, 10)
    int fb = 0;
#pragma unroll 1
    for (int it = 0; it < 6; ++it) {
        ENC_COMP(A, fb)
        ENC_LOAD(A, fb + 20)
        ENC_COMP(Bf, fb + 10)
        ENC_LOAD(Bf, fb + 30)
        fb += 20;
    }
    ENC_COMP(A, 120)
    ENC_LOAD(A, 140)
    ENC_COMP(Bf, 130)
    ENC_COMP(A, 140)

#pragma unroll
    for (int j = 0; j < 30; ++j) h1[j] = sp_f(h1[j]);

    float h2[30];
#pragma unroll
    for (int j = 0; j < 30; ++j) h2[j] = w[5430 + j];
    for (int j1 = 0; j1 < 30; ++j1) {
        float hv = h1[j1];
#pragma unroll
        for (int j = 0; j < 30; ++j) h2[j] = fmaf(hv, w[4530 + j1 * 30 + j], h2[j]);
    }
#pragma unroll
    for (int j = 0; j < 30; ++j) h2[j] = sp_f(h2[j]);

    float o12 = w[5910 + 12], o13 = w[5910 + 13], o14 = w[5910 + 14];
#pragma unroll
    for (int j2 = 0; j2 < 30; ++j2) {
        o12 = fmaf(h2[j2], w[5460 + j2 * 15 + 12], o12);
        o13 = fmaf(h2[j2], w[5460 + j2 * 15 + 13], o13);
        o14 = fmaf(h2[j2], w[5460 + j2 * 15 + 14], o14);
    }
    float* cp = ctx + (size_t)gid * 3;
    cp[0] = o12; cp[1] = o13; cp[2] = o14;

    if (blockIdx.x < 8) {   // tt == 0
        int b = gid;
        float o[12];
#pragma unroll
        for (int j3 = 0; j3 < 12; ++j3) o[j3] = w[5910 + j3];
#pragma unroll
        for (int j2 = 0; j2 < 30; ++j2) {
            float hv = h2[j2];
#pragma unroll
            for (int j3 = 0; j3 < 12; ++j3) o[j3] = fmaf(hv, w[5460 + j2 * 15 + j3], o[j3]);
        }
#pragma unroll
        for (int d = 0; d < 6; ++d) { qm[b * 6 + d] = o[d]; qs[b * 6 + d] = o[6 + d]; }
    }
}

// ------------------------------------------------------------------- SDE scan
// Wave-specialized: 128-thread blocks (2 waves) per chain, grid = 2048
// -> 16 waves/CU (4/SIMD). Wave A (tid<64): f/h networks + 64-lane butterfly.
// Wave B: g-network on 8-lane groups + path integrand + chain KL.
// Exchange via double-buffered LDS slots, ONE converged __syncthreads per step.
// Both waves redo the z-update from identical LDS inputs -> bitwise-equal z.
__global__ __launch_bounds__(128, 4) void scan_kernel(
    const float* __restrict__ ts, const float* __restrict__ dWall,
    const float* __restrict__ fW1, const float* __restrict__ fb1,
    const float* __restrict__ fW2, const float* __restrict__ fb2,
    const float* __restrict__ hW1, const float* __restrict__ hb1,
    const float* __restrict__ hW2, const float* __restrict__ hb2,
    const float* __restrict__ gW1, const float* __restrict__ gb1,
    const float* __restrict__ gW2, const float* __restrict__ gb2,
    const float* __restrict__ ctx,
    const float* __restrict__ qm, const float* __restrict__ qs,
    const float* __restrict__ eps0, const float* __restrict__ pm,
    const float* __restrict__ ps,
    float* __restrict__ zsb, float* __restrict__ acc)
{
    int tid = threadIdx.x;
    int lane = tid & 63;
    int b = blockIdx.x;
    bool isA = tid < 64;

    __shared__ float sRec[99 * 12];   // [0..5]=dW, [6..8]=ctx(k+1), [9]=t, [10]=dt
    __shared__ float exF[2][16];      // fvv[0..5], dfh[0..5]
    __shared__ float exG[2][16];      // {g,rg} pairs: [2d]=g_d, [2d+1]=rg_d

    // ---- bulk staging (128 threads) -----------------------------------
    for (int i = tid; i < 99 * 3; i += 128) {          // dW (float2 x3 per k)
        int k = i / 3, e = i % 3;
        float2 v = *(const float2*)(dWall + ((size_t)k * Bn + b) * 6 + e * 2);
        *(float2*)&sRec[k * 12 + e * 2] = v;
    }
    for (int i = tid; i < 99 * 3; i += 128) {          // ctx rows k+1
        int k = i / 3, e = i % 3;
        sRec[k * 12 + 6 + e] = ctx[((size_t)(k + 1) * Bn + b) * 3 + e];
    }
    for (int i = tid; i < 99; i += 128) {              // t, dt
        float t0 = ts[i], t1 = ts[i + 1];
        sRec[i * 12 + 9]  = t0;
        sRec[i * 12 + 10] = t1 - t0;
        sRec[i * 12 + 11] = 0.f;
    }

    // ---- z0 (identical on all 128 lanes; uniform broadcast loads) ------
    float z[6];
#pragma unroll
    for (int d = 0; d < 6; ++d) {
        float m = qm[b * 6 + d];
        float sq = __expf(clamp6(qs[b * 6 + d]));
        z[d] = fmaf(sq, eps0[b * 6 + d], m);
    }
    if (tid == 0) {                                    // zs[0] row
        float* zp = zsb + (size_t)b * 6;
        *(float2*)(zp)     = make_float2(z[0], z[1]);
        *(float2*)(zp + 2) = make_float2(z[2], z[3]);
        *(float2*)(zp + 4) = make_float2(z[4], z[5]);
    }
    if (tid == 64) {                                   // chain KL partial
        float klsum = 0.f;
#pragma unroll
        for (int d = 0; d < 6; ++d) {
            float m = qm[b * 6 + d];
            float sq = __expf(clamp6(qs[b * 6 + d]));
            float spz = __expf(clamp6(ps[d]));
            float dm = m - pm[d];
            klsum += __logf(spz / sq) + (sq * sq + dm * dm) / (2.f * spz * spz) - 0.5f;
        }
        atomicAdd(&acc[1], klsum);
    }

    // ---- per-wave weights ---------------------------------------------
    // Wave A: f/h column weights (valid only for tid<64)
    float wl1[10], b1w, wl2[6], fb2v[6], hb2v[6];
    // Wave B: g unit weights
    float gwa[4], gwb[4], gw2v[4], gbb[4], gb2v;
    int dL = 0;
    if (isA) {
        bool lower = lane < 32;
        int j = lane & 31;
        int jc = (j < 30) ? j : 29;
        bool jvalid = (j < 30);
#pragma unroll
        for (int i = 0; i < 10; ++i)
            wl1[i] = lower ? fW1[i * 30 + jc] : (i < 7 ? hW1[i * 30 + jc] : 0.f);
        b1w = lower ? fb1[jc] : hb1[jc];
#pragma unroll
        for (int d = 0; d < 6; ++d)
            wl2[d] = jvalid ? (lower ? fW2[jc * 6 + d] : hW2[jc * 6 + d]) : 0.f;
#pragma unroll
        for (int d = 0; d < 6; ++d) { fb2v[d] = fb2[d]; hb2v[d] = hb2[d]; }
    } else {
        int dL8 = lane >> 3;
        dL = (dL8 < 6) ? dL8 : 0;
        int s = lane & 7;
#pragma unroll
        for (int u = 0; u < 4; ++u) {
            int jj = s + 8 * u;
            bool ok = (dL8 < 6) && (jj < 30);
            gwa[u]  = ok ? gW1[dL * 60 + jj] : 0.f;        // t coeff
            gwb[u]  = ok ? gW1[dL * 60 + 30 + jj] : 0.f;   // z coeff
            gw2v[u] = ok ? gW2[dL * 30 + jj] : 0.f;
            gbb[u]  = ok ? gb1[dL * 30 + jj] : 0.f;
        }
        gb2v = gb2[dL];
    }

    __syncthreads();

    float pacc = 0.f;

    for (int k = 0; k < Tn - 1; ++k) {
        int kb = k & 1;
        float4 r0 = *(float4*)&sRec[k * 12];       // dw0..3
        float4 r1 = *(float4*)&sRec[k * 12 + 4];   // dw4,dw5,c0,c1
        float4 r2 = *(float4*)&sRec[k * 12 + 8];   // c2,t,dt,pad
        float t = r2.y, dt = r2.z;

        if (isA) {
            // ---- f/h hidden: one column per lane ----------------------
            float a = fmaf(t, wl1[0], b1w);
#pragma unroll
            for (int i = 0; i < 6; ++i) a = fmaf(z[i], wl1[1 + i], a);
            a = fmaf(r1.z, wl1[7], a);
            a = fmaf(r1.w, wl1[8], a);
            a = fmaf(r2.x, wl1[9], a);
            float hid = sp_f(a);

            float pp[6];
#pragma unroll
            for (int d = 0; d < 6; ++d) pp[d] = hid * wl2[d];
#pragma unroll
            for (int d = 0; d < 6; ++d) pp[d] += dpp_xor1(pp[d]);
#pragma unroll
            for (int d = 0; d < 6; ++d) pp[d] += dpp_xor2(pp[d]);
#pragma unroll
            for (int d = 0; d < 6; ++d) pp[d] += dpp_hmirror(pp[d]);
#pragma unroll
            for (int d = 0; d < 6; ++d) pp[d] += dpp_ror8(pp[d]);
#pragma unroll
            for (int d = 0; d < 6; ++d) pp[d] = xor16_sum(pp[d]);
            float fvv[6], dfh[6];
            bool lower = lane < 32;
#pragma unroll
            for (int d = 0; d < 6; ++d) {
                float oth = other_half(pp[d]);
                float fsum = lower ? pp[d] : oth;
                float hsum = lower ? oth : pp[d];
                fvv[d] = fsum + fb2v[d];
                dfh[d] = fvv[d] - (hsum + hb2v[d]);
            }
            if (lane == 0) {
                *(float4*)&exF[kb][0] = make_float4(fvv[0], fvv[1], fvv[2], fvv[3]);
                *(float4*)&exF[kb][4] = make_float4(fvv[4], fvv[5], dfh[0], dfh[1]);
                *(float4*)&exF[kb][8] = make_float4(dfh[2], dfh[3], dfh[4], dfh[5]);
            }
        } else {
            // ---- g: own-dim z, 4 units/lane, 8-lane-group reduce ------
            float zq = z[0];
            zq = (dL == 1) ? z[1] : zq;
            zq = (dL == 2) ? z[2] : zq;
            zq = (dL == 3) ? z[3] : zq;
            zq = (dL == 4) ? z[4] : zq;
            zq = (dL == 5) ? z[5] : zq;
            float ga = 0.f;
#pragma unroll
            for (int u = 0; u < 4; ++u) {
                float pre = fmaf(t, gwa[u], gbb[u]);
                pre = fmaf(zq, gwb[u], pre);
                ga = fmaf(sp_f(pre), gw2v[u], ga);
            }
            ga += dpp_xor1(ga);
            ga += dpp_xor2(ga);
            ga += dpp_hmirror(ga);
            float gacc = ga + gb2v;
            float e = __expf(-gacc);
            float rg = 1.f + e;                          // = 1/sigmoid(gacc)
            float gval = __builtin_amdgcn_rcpf(rg);
            if ((lane & 7) == 0 && (lane >> 3) < 6)
                *(float2*)&exG[kb][2 * dL] = make_float2(gval, rg);
        }

        __syncthreads();   // single converged barrier per step

        // ---- converged tail: both waves update z identically ----------
        float4 f03 = *(float4*)&exF[kb][0];
        float4 f47 = *(float4*)&exF[kb][4];
        float4 d25 = *(float4*)&exF[kb][8];
        float4 e01 = *(float4*)&exG[kb][0];
        float4 e23 = *(float4*)&exG[kb][4];
        float4 e45 = *(float4*)&exG[kb][8];
        float fvv[6] = { f03.x, f03.y, f03.z, f03.w, f47.x, f47.y };
        float dfh[6] = { f47.z, f47.w, d25.x, d25.y, d25.z, d25.w };
        float gl[6]  = { e01.x, e01.z, e23.x, e23.z, e45.x, e45.z };
        float rgv[6] = { e01.y, e01.w, e23.y, e23.w, e45.y, e45.w };

        if (!isA) {
            float s2 = 0.f;
#pragma unroll
            for (int d = 0; d < 6; ++d) {
                float u = dfh[d] * rgv[d];
                s2 = fmaf(u, u, s2);
            }
            pacc = fmaf(0.5f * dt, s2, pacc);
        }

        float dwv[6] = { r0.x, r0.y, r0.z, r0.w, r1.x, r1.y };
#pragma unroll
        for (int d = 0; d < 6; ++d)
            z[d] = fmaf(gl[d], dwv[d], fmaf(fvv[d], dt, z[d]));

        if (tid == 0) {
            float* zp = zsb + ((size_t)(k + 1) * Bn + b) * 6;
            *(float2*)(zp)     = make_float2(z[0], z[1]);
            *(float2*)(zp + 2) = make_float2(z[2], z[3]);
            *(float2*)(zp + 4) = make_float2(z[4], z[5]);
        }
    }
    if (tid == 64) atomicAdd(&acc[2], pacc);   // pacc identical on wave B
}

// ------------------------------------------------------ decoder + likelihood
__global__ __launch_bounds__(256) void dec_kernel(
    const float* __restrict__ zsb, const float* __restrict__ xs,
    const float* __restrict__ dcW1, const float* __restrict__ dcb1,
    const float* __restrict__ dcW2, const float* __restrict__ dcb2,
    const float* __restrict__ dcW3, const float* __restrict__ dcb3,
    float* __restrict__ acc)
{
    __shared__ float w[4240];
    for (int i = threadIdx.x; i < 180; i += 256) w[i] = dcW1[i];
    if (threadIdx.x < 30) w[180 + threadIdx.x] = dcb1[threadIdx.x];
    for (int i = threadIdx.x; i < 900; i += 256) w[210 + i] = dcW2[i];
    if (threadIdx.x < 30) w[1110 + threadIdx.x] = dcb2[threadIdx.x];
    for (int i = threadIdx.x; i < 3000; i += 256) {
        int j2 = i / 100, j3 = i % 100;
        w[1140 + j3 * 30 + j2] = dcW3[i];
    }
    for (int i = threadIdx.x; i < 100; i += 256) w[4140 + i] = dcb3[i];
    __syncthreads();

    int gid = blockIdx.x * 256 + threadIdx.x;       // = t*Bn + b

    const float* tg = xs + (size_t)gid * 150 + 100;   // xs[:,:,-1,:]
    float2 tgv[25];
#pragma unroll
    for (int i = 0; i < 25; ++i) tgv[i] = *(const float2*)(tg + 2 * i);

    const float* zp = zsb + (size_t)gid * 6;
    float zv[6];
#pragma unroll
    for (int i = 0; i < 3; ++i) {
        float2 zv2 = *(const float2*)(zp + 2 * i);
        zv[2 * i] = zv2.x; zv[2 * i + 1] = zv2.y;
    }

    float h1[30];
#pragma unroll
    for (int j = 0; j < 30; ++j) h1[j] = w[180 + j];
#pragma unroll
    for (int i = 0; i < 6; ++i) {
        float zi = zv[i];
#pragma unroll
        for (int j = 0; j < 30; ++j) h1[j] = fmaf(zi, w[i * 30 + j], h1[j]);
    }
#pragma unroll
    for (int j = 0; j < 30; ++j) h1[j] = sp_f(h1[j]);

    float h2[30];
#pragma unroll
    for (int j = 0; j < 30; ++j) h2[j] = w[1110 + j];
    for (int j1 = 0; j1 < 30; ++j1) {
        float hv = h1[j1];
#pragma unroll
        for (int j = 0; j < 30; ++j) h2[j] = fmaf(hv, w[210 + j1 * 30 + j], h2[j]);
    }
#pragma unroll
    for (int j = 0; j < 30; ++j) h2[j] = sp_f(h2[j]);

    float lpacc = 0.f;
#pragma unroll
    for (int ff = 0; ff < 50; ++ff) {
        float xm = w[4140 + ff], xl = w[4140 + 50 + ff];
#pragma unroll
        for (int j2 = 0; j2 < 30; ++j2) {
            xm = fmaf(h2[j2], w[1140 + ff * 30 + j2], xm);
            xl = fmaf(h2[j2], w[1140 + (50 + ff) * 30 + j2], xl);
        }
        float cl = clamp6(xl);
        float tv = (ff & 1) ? tgv[ff >> 1].y : tgv[ff >> 1].x;
        float u = (tv - xm) * __expf(-cl);
        lpacc += -0.5f * u * u - cl - 0.91893853320467274f;
    }
#pragma unroll
    for (int mm = 1; mm <= 32; mm <<= 1) lpacc += __shfl_xor(lpacc, mm);
    __shared__ float red[4];
    if ((threadIdx.x & 63) == 0) red[threadIdx.x >> 6] = lpacc;
    __syncthreads();
    if (threadIdx.x == 0) atomicAdd(&acc[0], red[0] + red[1] + red[2] + red[3]);
}

__global__ void final_kernel(const float* __restrict__ acc, float* __restrict__ out)
{
    out[0] = acc[0] * (1.f / (float)Bn);
    out[1] = (acc[1] + acc[2]) * (1.f / (float)Bn);
}

// --------------------------------------------------------------------- launch
extern "C" void kernel_launch(void* const* d_in, const int* in_sizes, int n_in,
                              void* d_out, int out_size, void* d_ws, size_t ws_size,
                              hipStream_t stream)
{
    const float* xs   = (const float*)d_in[0];
    const float* ts   = (const float*)d_in[1];
    const float* eps0 = (const float*)d_in[2];
    const float* dW   = (const float*)d_in[3];
    const float* eW1  = (const float*)d_in[4];
    const float* eb1  = (const float*)d_in[5];
    const float* eW2  = (const float*)d_in[6];
    const float* eb2  = (const float*)d_in[7];
    const float* eW3  = (const float*)d_in[8];
    const float* eb3  = (const float*)d_in[9];
    const float* dcW1 = (const float*)d_in[10];
    const float* dcb1 = (const float*)d_in[11];
    const float* dcW2 = (const float*)d_in[12];
    const float* dcb2 = (const float*)d_in[13];
    const float* dcW3 = (const float*)d_in[14];
    const float* dcb3 = (const float*)d_in[15];
    const float* fW1  = (const float*)d_in[16];
    const float* fb1  = (const float*)d_in[17];
    const float* fW2  = (const float*)d_in[18];
    const float* fb2  = (const float*)d_in[19];
    const float* hW1  = (const float*)d_in[20];
    const float* hb1  = (const float*)d_in[21];
    const float* hW2  = (const float*)d_in[22];
    const float* hb2  = (const float*)d_in[23];
    const float* gW1  = (const float*)d_in[24];
    const float* gb1  = (const float*)d_in[25];
    const float* gW2  = (const float*)d_in[26];
    const float* gb2  = (const float*)d_in[27];
    const float* pm   = (const float*)d_in[28];
    const float* ps   = (const float*)d_in[29];

    float* ws  = (float*)d_ws;
    float* acc = ws;                    // [0]=S_lp, [1]=S_kl, [2]=S_path
    float* ctx = ws + 16;               // T*B*3 = 614400
    float* qm  = ctx + 614400;          // B*6
    float* qs  = qm + 12288;            // B*6
    float* zs  = qs + 12288;            // T*B*6 = 1228800
    float* out = (float*)d_out;

    hipMemsetAsync(acc, 0, 16 * sizeof(float), stream);
    enc_kernel<<<800, 256, 0, stream>>>(xs, eW1, eb1, eW2, eb2, eW3, eb3, ctx, qm, qs);
    scan_kernel<<<2048, 128, 0, stream>>>(ts, dW, fW1, fb1, fW2, fb2, hW1, hb1,
                                          hW2, hb2, gW1, gb1, gW2, gb2, ctx,
                                          qm, qs, eps0, pm, ps, zs, acc);
    dec_kernel<<<800, 256, 0, stream>>>(zs, xs, dcW1, dcb1, dcW2, dcb2, dcW3, dcb3, acc);
    final_kernel<<<1, 1, 0, stream>>>(acc, out);
}

// Round 7
// 271.854 us; speedup vs baseline: 2.4396x; 1.0560x over previous
//
#include <hip/hip_runtime.h>
#include <hip/hip_bf16.h>
#include <math.h>

#define Tn 100
#define Bn 2048

typedef int v2i __attribute__((ext_vector_type(2)));

__device__ __forceinline__ float sp_f(float x) {
    // jax.nn.softplus(x) = max(x,0) + log1p(exp(-|x|))
    float e = __expf(-fabsf(x));
    return fmaxf(x, 0.f) + __logf(1.f + e);
}
__device__ __forceinline__ float clamp6(float x) {
    return fminf(fmaxf(x, -6.f), 6.f);
}
// DPP cross-lane (pure VALU).
__device__ __forceinline__ float dpp_xor1(float x) {
    return __int_as_float(__builtin_amdgcn_mov_dpp(__float_as_int(x), 0xB1, 0xF, 0xF, 1));
}
__device__ __forceinline__ float dpp_xor2(float x) {
    return __int_as_float(__builtin_amdgcn_mov_dpp(__float_as_int(x), 0x4E, 0xF, 0xF, 1));
}
__device__ __forceinline__ float dpp_hmirror(float x) {   // == xor4 for quad-uniform
    return __int_as_float(__builtin_amdgcn_mov_dpp(__float_as_int(x), 0x141, 0xF, 0xF, 1));
}
__device__ __forceinline__ float dpp_ror8(float x) {      // == xor8 for 8-uniform
    return __int_as_float(__builtin_amdgcn_mov_dpp(__float_as_int(x), 0x128, 0xF, 0xF, 1));
}
template <int OFF>
__device__ __forceinline__ float swz(float x) {
    return __int_as_float(__builtin_amdgcn_ds_swizzle(__float_as_int(x), OFF));
}
__device__ __forceinline__ float xor16_sum(float x) {
#if __has_builtin(__builtin_amdgcn_permlane16_swap)
    v2i r = __builtin_amdgcn_permlane16_swap(__float_as_int(x), __float_as_int(x), false, false);
    return __int_as_float(r[0]) + __int_as_float(r[1]);
#else
    return x + swz<0x401F>(x);
#endif
}
__device__ __forceinline__ float other_half(float x) {
#if __has_builtin(__builtin_amdgcn_permlane32_swap)
    v2i r = __builtin_amdgcn_permlane32_swap(__float_as_int(x), __float_as_int(x), false, false);
    return (__int_as_float(r[0]) + __int_as_float(r[1])) - x;
#else
    return __shfl_xor(x, 32);
#endif
}

// h[0..29] += v * wrow[0..29]  (wrow 16B-aligned, stride-32 padded row)
__device__ __forceinline__ void row_fma(float* h, const float* wrow, float v) {
#pragma unroll
    for (int q = 0; q < 7; ++q) {
        float4 wv = *(const float4*)(wrow + 4 * q);
        h[4 * q + 0] = fmaf(v, wv.x, h[4 * q + 0]);
        h[4 * q + 1] = fmaf(v, wv.y, h[4 * q + 1]);
        h[4 * q + 2] = fmaf(v, wv.z, h[4 * q + 2]);
        h[4 * q + 3] = fmaf(v, wv.w, h[4 * q + 3]);
    }
    float2 wt = *(const float2*)(wrow + 28);
    h[28] = fmaf(v, wt.x, h[28]);
    h[29] = fmaf(v, wt.y, h[29]);
}
// dot(h[0..29], wrow[0..29]) with float4 LDS reads
__device__ __forceinline__ float dot30(const float* h, const float* wrow) {
    float a0 = 0.f, a1 = 0.f, a2 = 0.f, a3 = 0.f;
#pragma unroll
    for (int q = 0; q < 7; ++q) {
        float4 wv = *(const float4*)(wrow + 4 * q);
        a0 = fmaf(h[4 * q + 0], wv.x, a0);
        a1 = fmaf(h[4 * q + 1], wv.y, a1);
        a2 = fmaf(h[4 * q + 2], wv.z, a2);
        a3 = fmaf(h[4 * q + 3], wv.w, a3);
    }
    float2 wt = *(const float2*)(wrow + 28);
    a0 = fmaf(h[28], wt.x, a0);
    a1 = fmaf(h[29], wt.y, a1);
    return (a0 + a1) + (a2 + a3);
}

// ---------------------------------------------------------------- encoder
// LDS layout (floats), rows padded to stride 32 for b128 reads:
// eW1 rows: i*32, i<150 -> [0,4800) ; eb1 @4800 ; eW2 rows: 4832+j1*32 ;
// eb2 @5792 ; eW3 @5824 (j2*15+j3, scalar) ; eb3 @6274.
#define ENC_LOAD(buf, base)                                                   \
    _Pragma("unroll")                                                         \
    for (int i = 0; i < 5; ++i) buf[i] = *(const float2*)(x + (base) + 2 * i);
#define ENC_COMP(buf, base)                                                   \
    _Pragma("unroll")                                                         \
    for (int i = 0; i < 5; ++i) {                                             \
        row_fma(h1, &w[(base + 2 * i) * 32], buf[i].x);                       \
        row_fma(h1, &w[(base + 2 * i + 1) * 32], buf[i].y);                   \
    }

__global__ __launch_bounds__(256) void enc_kernel(
    const float* __restrict__ xs,
    const float* __restrict__ eW1, const float* __restrict__ eb1,
    const float* __restrict__ eW2, const float* __restrict__ eb2,
    const float* __restrict__ eW3, const float* __restrict__ eb3,
    float* __restrict__ ctx, float* __restrict__ qm, float* __restrict__ qs)
{
    __shared__ float w[6292];
    for (int i = threadIdx.x; i < 4500; i += 256) w[(i / 30) * 32 + (i % 30)] = eW1[i];
    if (threadIdx.x < 30) w[4800 + threadIdx.x] = eb1[threadIdx.x];
    for (int i = threadIdx.x; i < 900; i += 256) w[4832 + (i / 30) * 32 + (i % 30)] = eW2[i];
    if (threadIdx.x < 30) w[5792 + threadIdx.x] = eb2[threadIdx.x];
    for (int i = threadIdx.x; i < 450; i += 256) w[5824 + i] = eW3[i];
    if (threadIdx.x < 15) w[6274 + threadIdx.x] = eb3[threadIdx.x];
    __syncthreads();

    int gid = blockIdx.x * 256 + threadIdx.x;          // = tt*Bn + b
    const float* x = xs + (size_t)gid * 150;

    float h1[30];
#pragma unroll
    for (int j = 0; j < 30; ++j) h1[j] = w[4800 + j];

    float2 A[5], Bf[5];
    ENC_LOAD(A, 0)
    ENC_LOAD(Bf, 10)
    int fb = 0;
#pragma unroll 1
    for (int it = 0; it < 6; ++it) {
        ENC_COMP(A, fb)
        ENC_LOAD(A, fb + 20)
        ENC_COMP(Bf, fb + 10)
        ENC_LOAD(Bf, fb + 30)
        fb += 20;
    }
    ENC_COMP(A, 120)
    ENC_LOAD(A, 140)
    ENC_COMP(Bf, 130)
    ENC_COMP(A, 140)

#pragma unroll
    for (int j = 0; j < 30; ++j) h1[j] = sp_f(h1[j]);

    float h2[30];
#pragma unroll
    for (int j = 0; j < 30; ++j) h2[j] = w[5792 + j];
#pragma unroll
    for (int j1 = 0; j1 < 30; ++j1) row_fma(h2, &w[4832 + j1 * 32], h1[j1]);
#pragma unroll
    for (int j = 0; j < 30; ++j) h2[j] = sp_f(h2[j]);

    float o12 = w[6274 + 12], o13 = w[6274 + 13], o14 = w[6274 + 14];
#pragma unroll
    for (int j2 = 0; j2 < 30; ++j2) {
        o12 = fmaf(h2[j2], w[5824 + j2 * 15 + 12], o12);
        o13 = fmaf(h2[j2], w[5824 + j2 * 15 + 13], o13);
        o14 = fmaf(h2[j2], w[5824 + j2 * 15 + 14], o14);
    }
    float* cp = ctx + (size_t)gid * 3;
    cp[0] = o12; cp[1] = o13; cp[2] = o14;

    if (blockIdx.x < 8) {   // tt == 0
        int b = gid;
        float o[12];
#pragma unroll
        for (int j3 = 0; j3 < 12; ++j3) o[j3] = w[6274 + j3];
#pragma unroll
        for (int j2 = 0; j2 < 30; ++j2) {
            float hv = h2[j2];
#pragma unroll
            for (int j3 = 0; j3 < 12; ++j3) o[j3] = fmaf(hv, w[5824 + j2 * 15 + j3], o[j3]);
        }
#pragma unroll
        for (int d = 0; d < 6; ++d) { qm[b * 6 + d] = o[d]; qs[b * 6 + d] = o[6 + d]; }
    }
}

// ------------------------------------------------------------------- SDE scan
// Wave-specialized: 128-thread blocks (2 waves) per chain, grid = 2048.
__global__ __launch_bounds__(128, 4) void scan_kernel(
    const float* __restrict__ ts, const float* __restrict__ dWall,
    const float* __restrict__ fW1, const float* __restrict__ fb1,
    const float* __restrict__ fW2, const float* __restrict__ fb2,
    const float* __restrict__ hW1, const float* __restrict__ hb1,
    const float* __restrict__ hW2, const float* __restrict__ hb2,
    const float* __restrict__ gW1, const float* __restrict__ gb1,
    const float* __restrict__ gW2, const float* __restrict__ gb2,
    const float* __restrict__ ctx,
    const float* __restrict__ qm, const float* __restrict__ qs,
    const float* __restrict__ eps0, const float* __restrict__ pm,
    const float* __restrict__ ps,
    float* __restrict__ zsb, float* __restrict__ acc)
{
    int tid = threadIdx.x;
    int lane = tid & 63;
    int b = blockIdx.x;
    bool isA = tid < 64;

    __shared__ float sRec[99 * 12];   // [0..5]=dW, [6..8]=ctx(k+1), [9]=t, [10]=dt
    __shared__ float exF[2][16];      // fvv[0..5], dfh[0..5]
    __shared__ float exG[2][16];      // {g,rg} pairs

    for (int i = tid; i < 99 * 3; i += 128) {
        int k = i / 3, e = i % 3;
        float2 v = *(const float2*)(dWall + ((size_t)k * Bn + b) * 6 + e * 2);
        *(float2*)&sRec[k * 12 + e * 2] = v;
    }
    for (int i = tid; i < 99 * 3; i += 128) {
        int k = i / 3, e = i % 3;
        sRec[k * 12 + 6 + e] = ctx[((size_t)(k + 1) * Bn + b) * 3 + e];
    }
    for (int i = tid; i < 99; i += 128) {
        float t0 = ts[i], t1 = ts[i + 1];
        sRec[i * 12 + 9]  = t0;
        sRec[i * 12 + 10] = t1 - t0;
        sRec[i * 12 + 11] = 0.f;
    }

    float z[6];
#pragma unroll
    for (int d = 0; d < 6; ++d) {
        float m = qm[b * 6 + d];
        float sq = __expf(clamp6(qs[b * 6 + d]));
        z[d] = fmaf(sq, eps0[b * 6 + d], m);
    }
    if (tid == 0) {
        float* zp = zsb + (size_t)b * 6;
        *(float2*)(zp)     = make_float2(z[0], z[1]);
        *(float2*)(zp + 2) = make_float2(z[2], z[3]);
        *(float2*)(zp + 4) = make_float2(z[4], z[5]);
    }
    if (tid == 64) {
        float klsum = 0.f;
#pragma unroll
        for (int d = 0; d < 6; ++d) {
            float m = qm[b * 6 + d];
            float sq = __expf(clamp6(qs[b * 6 + d]));
            float spz = __expf(clamp6(ps[d]));
            float dm = m - pm[d];
            klsum += __logf(spz / sq) + (sq * sq + dm * dm) / (2.f * spz * spz) - 0.5f;
        }
        atomicAdd(&acc[1], klsum);
    }

    float wl1[10], b1w, wl2[6], fb2v[6], hb2v[6];
    float gwa[4], gwb[4], gw2v[4], gbb[4], gb2v;
    int dL = 0;
    if (isA) {
        bool lower = lane < 32;
        int j = lane & 31;
        int jc = (j < 30) ? j : 29;
        bool jvalid = (j < 30);
#pragma unroll
        for (int i = 0; i < 10; ++i)
            wl1[i] = lower ? fW1[i * 30 + jc] : (i < 7 ? hW1[i * 30 + jc] : 0.f);
        b1w = lower ? fb1[jc] : hb1[jc];
#pragma unroll
        for (int d = 0; d < 6; ++d)
            wl2[d] = jvalid ? (lower ? fW2[jc * 6 + d] : hW2[jc * 6 + d]) : 0.f;
#pragma unroll
        for (int d = 0; d < 6; ++d) { fb2v[d] = fb2[d]; hb2v[d] = hb2[d]; }
    } else {
        int dL8 = lane >> 3;
        dL = (dL8 < 6) ? dL8 : 0;
        int s = lane & 7;
#pragma unroll
        for (int u = 0; u < 4; ++u) {
            int jj = s + 8 * u;
            bool ok = (dL8 < 6) && (jj < 30);
            gwa[u]  = ok ? gW1[dL * 60 + jj] : 0.f;
            gwb[u]  = ok ? gW1[dL * 60 + 30 + jj] : 0.f;
            gw2v[u] = ok ? gW2[dL * 30 + jj] : 0.f;
            gbb[u]  = ok ? gb1[dL * 30 + jj] : 0.f;
        }
        gb2v = gb2[dL];
    }

    __syncthreads();

    float pacc = 0.f;

    for (int k = 0; k < Tn - 1; ++k) {
        int kb = k & 1;
        float4 r0 = *(float4*)&sRec[k * 12];
        float4 r1 = *(float4*)&sRec[k * 12 + 4];
        float4 r2 = *(float4*)&sRec[k * 12 + 8];
        float t = r2.y, dt = r2.z;

        if (isA) {
            float a = fmaf(t, wl1[0], b1w);
#pragma unroll
            for (int i = 0; i < 6; ++i) a = fmaf(z[i], wl1[1 + i], a);
            a = fmaf(r1.z, wl1[7], a);
            a = fmaf(r1.w, wl1[8], a);
            a = fmaf(r2.x, wl1[9], a);
            float hid = sp_f(a);

            float pp[6];
#pragma unroll
            for (int d = 0; d < 6; ++d) pp[d] = hid * wl2[d];
#pragma unroll
            for (int d = 0; d < 6; ++d) pp[d] += dpp_xor1(pp[d]);
#pragma unroll
            for (int d = 0; d < 6; ++d) pp[d] += dpp_xor2(pp[d]);
#pragma unroll
            for (int d = 0; d < 6; ++d) pp[d] += dpp_hmirror(pp[d]);
#pragma unroll
            for (int d = 0; d < 6; ++d) pp[d] += dpp_ror8(pp[d]);
#pragma unroll
            for (int d = 0; d < 6; ++d) pp[d] = xor16_sum(pp[d]);
            float fvv[6], dfh[6];
            bool lower = lane < 32;
#pragma unroll
            for (int d = 0; d < 6; ++d) {
                float oth = other_half(pp[d]);
                float fsum = lower ? pp[d] : oth;
                float hsum = lower ? oth : pp[d];
                fvv[d] = fsum + fb2v[d];
                dfh[d] = fvv[d] - (hsum + hb2v[d]);
            }
            if (lane == 0) {
                *(float4*)&exF[kb][0] = make_float4(fvv[0], fvv[1], fvv[2], fvv[3]);
                *(float4*)&exF[kb][4] = make_float4(fvv[4], fvv[5], dfh[0], dfh[1]);
                *(float4*)&exF[kb][8] = make_float4(dfh[2], dfh[3], dfh[4], dfh[5]);
            }
        } else {
            float zq = z[0];
            zq = (dL == 1) ? z[1] : zq;
            zq = (dL == 2) ? z[2] : zq;
            zq = (dL == 3) ? z[3] : zq;
            zq = (dL == 4) ? z[4] : zq;
            zq = (dL == 5) ? z[5] : zq;
            float ga = 0.f;
#pragma unroll
            for (int u = 0; u < 4; ++u) {
                float pre = fmaf(t, gwa[u], gbb[u]);
                pre = fmaf(zq, gwb[u], pre);
                ga = fmaf(sp_f(pre), gw2v[u], ga);
            }
            ga += dpp_xor1(ga);
            ga += dpp_xor2(ga);
            ga += dpp_hmirror(ga);
            float gacc = ga + gb2v;
            float e = __expf(-gacc);
            float rg = 1.f + e;
            float gval = __builtin_amdgcn_rcpf(rg);
            if ((lane & 7) == 0 && (lane >> 3) < 6)
                *(float2*)&exG[kb][2 * dL] = make_float2(gval, rg);
        }

        __syncthreads();

        float4 f03 = *(float4*)&exF[kb][0];
        float4 f47 = *(float4*)&exF[kb][4];
        float4 d25 = *(float4*)&exF[kb][8];
        float4 e01 = *(float4*)&exG[kb][0];
        float4 e23 = *(float4*)&exG[kb][4];
        float4 e45 = *(float4*)&exG[kb][8];
        float fvv[6] = { f03.x, f03.y, f03.z, f03.w, f47.x, f47.y };
        float dfh[6] = { f47.z, f47.w, d25.x, d25.y, d25.z, d25.w };
        float gl[6]  = { e01.x, e01.z, e23.x, e23.z, e45.x, e45.z };
        float rgv[6] = { e01.y, e01.w, e23.y, e23.w, e45.y, e45.w };

        if (!isA) {
            float s2 = 0.f;
#pragma unroll
            for (int d = 0; d < 6; ++d) {
                float u = dfh[d] * rgv[d];
                s2 = fmaf(u, u, s2);
            }
            pacc = fmaf(0.5f * dt, s2, pacc);
        }

        float dwv[6] = { r0.x, r0.y, r0.z, r0.w, r1.x, r1.y };
#pragma unroll
        for (int d = 0; d < 6; ++d)
            z[d] = fmaf(gl[d], dwv[d], fmaf(fvv[d], dt, z[d]));

        if (tid == 0) {
            float* zp = zsb + ((size_t)(k + 1) * Bn + b) * 6;
            *(float2*)(zp)     = make_float2(z[0], z[1]);
            *(float2*)(zp + 2) = make_float2(z[2], z[3]);
            *(float2*)(zp + 4) = make_float2(z[4], z[5]);
        }
    }
    if (tid == 64) atomicAdd(&acc[2], pacc);
}

// ------------------------------------------------------ decoder + likelihood
// LDS layout: dcW1 rows i*32 (i<6) ; dcb1 @192 ; dcW2 rows 224+j1*32 ;
// dcb2 @1184 ; dcW3T rows 1216+j3*32 (j3<100, col j2) ; dcb3 @4416.
__global__ __launch_bounds__(256) void dec_kernel(
    const float* __restrict__ zsb, const float* __restrict__ xs,
    const float* __restrict__ dcW1, const float* __restrict__ dcb1,
    const float* __restrict__ dcW2, const float* __restrict__ dcb2,
    const float* __restrict__ dcW3, const float* __restrict__ dcb3,
    float* __restrict__ acc)
{
    __shared__ float w[4516];
    for (int i = threadIdx.x; i < 180; i += 256) w[(i / 30) * 32 + (i % 30)] = dcW1[i];
    if (threadIdx.x < 30) w[192 + threadIdx.x] = dcb1[threadIdx.x];
    for (int i = threadIdx.x; i < 900; i += 256) w[224 + (i / 30) * 32 + (i % 30)] = dcW2[i];
    if (threadIdx.x < 30) w[1184 + threadIdx.x] = dcb2[threadIdx.x];
    for (int i = threadIdx.x; i < 3000; i += 256) {
        int j2 = i / 100, j3 = i % 100;
        w[1216 + j3 * 32 + j2] = dcW3[i];
    }
    for (int i = threadIdx.x; i < 100; i += 256) w[4416 + i] = dcb3[i];
    __syncthreads();

    int gid = blockIdx.x * 256 + threadIdx.x;       // = t*Bn + b

    const float* tg = xs + (size_t)gid * 150 + 100;   // xs[:,:,-1,:]
    float2 tgv[25];
#pragma unroll
    for (int i = 0; i < 25; ++i) tgv[i] = *(const float2*)(tg + 2 * i);

    const float* zp = zsb + (size_t)gid * 6;
    float zv[6];
#pragma unroll
    for (int i = 0; i < 3; ++i) {
        float2 zv2 = *(const float2*)(zp + 2 * i);
        zv[2 * i] = zv2.x; zv[2 * i + 1] = zv2.y;
    }

    float h1[30];
#pragma unroll
    for (int j = 0; j < 30; ++j) h1[j] = w[192 + j];
#pragma unroll
    for (int i = 0; i < 6; ++i) row_fma(h1, &w[i * 32], zv[i]);
#pragma unroll
    for (int j = 0; j < 30; ++j) h1[j] = sp_f(h1[j]);

    float h2[30];
#pragma unroll
    for (int j = 0; j < 30; ++j) h2[j] = w[1184 + j];
#pragma unroll
    for (int j1 = 0; j1 < 30; ++j1) row_fma(h2, &w[224 + j1 * 32], h1[j1]);
#pragma unroll
    for (int j = 0; j < 30; ++j) h2[j] = sp_f(h2[j]);

    float lpacc = 0.f;
#pragma unroll
    for (int ff = 0; ff < 50; ++ff) {
        float xm = w[4416 + ff]      + dot30(h2, &w[1216 + ff * 32]);
        float xl = w[4416 + 50 + ff] + dot30(h2, &w[1216 + (50 + ff) * 32]);
        float cl = clamp6(xl);
        float tv = (ff & 1) ? tgv[ff >> 1].y : tgv[ff >> 1].x;
        float u = (tv - xm) * __expf(-cl);
        lpacc += -0.5f * u * u - cl - 0.91893853320467274f;
    }
#pragma unroll
    for (int mm = 1; mm <= 32; mm <<= 1) lpacc += __shfl_xor(lpacc, mm);
    __shared__ float red[4];
    if ((threadIdx.x & 63) == 0) red[threadIdx.x >> 6] = lpacc;
    __syncthreads();
    if (threadIdx.x == 0) atomicAdd(&acc[0], red[0] + red[1] + red[2] + red[3]);
}

__global__ void final_kernel(const float* __restrict__ acc, float* __restrict__ out)
{
    out[0] = acc[0] * (1.f / (float)Bn);
    out[1] = (acc[1] + acc[2]) * (1.f / (float)Bn);
}

// --------------------------------------------------------------------- launch
extern "C" void kernel_launch(void* const* d_in, const int* in_sizes, int n_in,
                              void* d_out, int out_size, void* d_ws, size_t ws_size,
                              hipStream_t stream)
{
    const float* xs   = (const float*)d_in[0];
    const float* ts   = (const float*)d_in[1];
    const float* eps0 = (const float*)d_in[2];
    const float* dW   = (const float*)d_in[3];
    const float* eW1  = (const float*)d_in[4];
    const float* eb1  = (const float*)d_in[5];
    const float* eW2  = (const float*)d_in[6];
    const float* eb2  = (const float*)d_in[7];
    const float* eW3  = (const float*)d_in[8];
    const float* eb3  = (const float*)d_in[9];
    const float* dcW1 = (const float*)d_in[10];
    const float* dcb1 = (const float*)d_in[11];
    const float* dcW2 = (const float*)d_in[12];
    const float* dcb2 = (const float*)d_in[13];
    const float* dcW3 = (const float*)d_in[14];
    const float* dcb3 = (const float*)d_in[15];
    const float* fW1  = (const float*)d_in[16];
    const float* fb1  = (const float*)d_in[17];
    const float* fW2  = (const float*)d_in[18];
    const float* fb2  = (const float*)d_in[19];
    const float* hW1  = (const float*)d_in[20];
    const float* hb1  = (const float*)d_in[21];
    const float* hW2  = (const float*)d_in[22];
    const float* hb2  = (const float*)d_in[23];
    const float* gW1  = (const float*)d_in[24];
    const float* gb1  = (const float*)d_in[25];
    const float* gW2  = (const float*)d_in[26];
    const float* gb2  = (const float*)d_in[27];
    const float* pm   = (const float*)d_in[28];
    const float* ps   = (const float*)d_in[29];

    float* ws  = (float*)d_ws;
    float* acc = ws;                    // [0]=S_lp, [1]=S_kl, [2]=S_path
    float* ctx = ws + 16;               // T*B*3 = 614400
    float* qm  = ctx + 614400;          // B*6
    float* qs  = qm + 12288;            // B*6
    float* zs  = qs + 12288;            // T*B*6 = 1228800
    float* out = (float*)d_out;

    hipMemsetAsync(acc, 0, 16 * sizeof(float), stream);
    enc_kernel<<<800, 256, 0, stream>>>(xs, eW1, eb1, eW2, eb2, eW3, eb3, ctx, qm, qs);
    scan_kernel<<<2048, 128, 0, stream>>>(ts, dW, fW1, fb1, fW2, fb2, hW1, hb1,
                                          hW2, hb2, gW1, gb1, gW2, gb2, ctx,
                                          qm, qs, eps0, pm, ps, zs, acc);
    dec_kernel<<<800, 256, 0, stream>>>(zs, xs, dcW1, dcb1, dcW2, dcb2, dcW3, dcb3, acc);
    final_kernel<<<1, 1, 0, stream>>>(acc, out);
}